// Round 10
// baseline (901.844 us; speedup 1.0000x reference)
//
#include <hip/hip_runtime.h>

#define NN 32768      // total nodes
#define GG 256        // graphs
#define NPGN 128      // nodes per graph
#define ET 524288     // total directed edges
#define EH 262144     // edges per direction
#define D1 128        // input feature dim
#define D2 256        // hidden dim
#define RR 200        // relations

typedef unsigned short u16;
typedef __attribute__((ext_vector_type(8))) short bf16x8;   // MFMA A/B frag (4 VGPR)
typedef __attribute__((ext_vector_type(4))) float f32x4;    // MFMA C/D frag
typedef __attribute__((ext_vector_type(8))) unsigned short u16x8;

__device__ __forceinline__ float bf2f(u16 u) {
    union { unsigned int i; float f; } v; v.i = ((unsigned int)u) << 16; return v.f;
}
__device__ __forceinline__ u16 f2bf(float f) {
    union { unsigned int i; float f; } v; v.f = f;
    unsigned int x = v.i;
    return (u16)((x + 0x7fffu + ((x >> 16) & 1u)) >> 16);   // RNE
}

// ---- histograms: by-src (for norm) and by-dst (for CSR) per direction ----
__global__ void k_hist(const int* __restrict__ ei, int* __restrict__ hs_in,
                       int* __restrict__ hs_out, int* __restrict__ hd_in,
                       int* __restrict__ hd_out) {
    int e = blockIdx.x * blockDim.x + threadIdx.x;
    if (e >= ET) return;
    int s = ei[e], d = ei[ET + e];
    if (e < EH) { atomicAdd(&hs_in[s], 1);  atomicAdd(&hd_in[d], 1); }
    else        { atomicAdd(&hs_out[s], 1); atomicAdd(&hd_out[d], 1); }
}

__global__ void k_dinv(const int* __restrict__ hs_in, const int* __restrict__ hs_out,
                       float* __restrict__ dinv_in, float* __restrict__ dinv_out) {
    int n = blockIdx.x * blockDim.x + threadIdx.x;
    if (n >= NN) return;
    int a = hs_in[n], b = hs_out[n];
    dinv_in[n]  = a > 0 ? rsqrtf((float)a) : 0.f;
    dinv_out[n] = b > 0 ? rsqrtf((float)b) : 0.f;
}

// ---- exclusive scan of 32768 ints, single block of 1024 ----
__global__ __launch_bounds__(1024) void k_scan(const int* __restrict__ hist,
                                               int* __restrict__ off) {
    __shared__ int lds[1024];
    int t = threadIdx.x;
    int base = t * 32;
    int loc[32];
    int s = 0;
#pragma unroll
    for (int i = 0; i < 32; ++i) { loc[i] = s; s += hist[base + i]; }
    lds[t] = s;
    int tot = s;
    __syncthreads();
    for (int st = 1; st < 1024; st <<= 1) {
        int v = (t >= st) ? lds[t - st] : 0;
        __syncthreads();
        lds[t] += v;
        __syncthreads();
    }
    int excl = lds[t] - tot;
#pragma unroll
    for (int i = 0; i < 32; ++i) off[base + i] = excl + loc[i];
    if (t == 1023) off[NN] = lds[1023];
}

// ---- fill CSR slots (dst-sorted); norm folded in ----
__global__ void k_fill(const int* __restrict__ ei, const int* __restrict__ et,
                       const float* __restrict__ dinv, const int* __restrict__ off,
                       int* __restrict__ cur, int* __restrict__ c_src,
                       int* __restrict__ c_et, float* __restrict__ c_norm, int eoff) {
    int e = blockIdx.x * blockDim.x + threadIdx.x;
    if (e >= EH) return;
    int s = ei[eoff + e], d = ei[ET + eoff + e], t = et[eoff + e];
    int slot = off[d] + atomicAdd(&cur[d], 1);
    c_src[slot] = s;
    c_et[slot] = t;
    c_norm[slot] = dinv[s] * dinv[d];
}

// ---- f32 -> bf16 ----
__global__ void k_convx(const float* __restrict__ in, u16* __restrict__ out, int n) {
    int i = blockIdx.x * blockDim.x + threadIdx.x;
    if (i < n) out[i] = f2bf(in[i]);
}

// ---- weight prep: Wt[l][n][k] = bf16(W[l][k][n]), lr folded into loop family ----
__global__ void k_prepw(const float* __restrict__ Wi, const float* __restrict__ Wo,
                        const float* __restrict__ Wl, const float* __restrict__ lr,
                        u16* __restrict__ WiT, u16* __restrict__ WoT,
                        u16* __restrict__ WlT, int K, int L) {
    int idx = blockIdx.x * blockDim.x + threadIdx.x;
    int per = L * K * 256;
    if (idx >= 3 * per) return;
    int fam = idx / per, rem = idx % per;
    int l = rem / (K * 256), rr = rem % (K * 256);
    int k = rr / 256, n = rr % 256;
    const float* src = fam == 0 ? Wi : fam == 1 ? Wo : Wl;
    float v = src[((size_t)l * K + k) * 256 + n];
    if (fam == 2) v *= lr[l * K + k];
    u16* dst = fam == 0 ? WiT : fam == 1 ? WoT : WlT;
    dst[((size_t)l * 256 + n) * K + k] = f2bf(v);
}

// ---- gather, feature-phase tiled: blockIdx.z picks 64 feats (4 MB x-slice = 1 XCD L2) ----
// 8 lanes/node, 32 nodes/block, R8's proven 4-edge unroll. Zeroes bnsums (block 0).
template <int K>
__global__ __launch_bounds__(256) void k_gather2(
    const u16* __restrict__ x, const u16* __restrict__ relb,
    const int* __restrict__ csI, const int* __restrict__ cetI,
    const float* __restrict__ cnI, const int* __restrict__ offI,
    const int* __restrict__ csO, const int* __restrict__ cetO,
    const float* __restrict__ cnO, const int* __restrict__ offO,
    u16* __restrict__ aggI, u16* __restrict__ aggO, float* __restrict__ bnsums) {
    if (blockIdx.x == 0 && blockIdx.y == 0 && blockIdx.z == 0 && threadIdx.x < 128)
        ((float4*)bnsums)[threadIdx.x] = make_float4(0.f, 0.f, 0.f, 0.f);
    const int dir = blockIdx.y;
    const int* __restrict__ cs  = dir ? csO : csI;
    const int* __restrict__ cet = dir ? cetO : cetI;
    const float* __restrict__ cn = dir ? cnO : cnI;
    const int* __restrict__ off = dir ? offO : offI;
    u16* __restrict__ agg = dir ? aggO : aggI;

    int node = blockIdx.x * 32 + (threadIdx.x >> 3);
    int c = blockIdx.z * 64 + (threadIdx.x & 7) * 8;
    int e0 = off[node], e1 = off[node + 1];
    float acc[8] = {};
    int e = e0;
    for (; e + 4 <= e1; e += 4) {
        int s0 = cs[e],  s1 = cs[e + 1],  s2 = cs[e + 2],  s3 = cs[e + 3];
        int t0 = cet[e], t1 = cet[e + 1], t2 = cet[e + 2], t3 = cet[e + 3];
        float n0 = cn[e], n1 = cn[e + 1], n2 = cn[e + 2], n3 = cn[e + 3];
        u16x8 xa = *(const u16x8*)(x + (size_t)s0 * K + c);
        u16x8 xb = *(const u16x8*)(x + (size_t)s1 * K + c);
        u16x8 xc = *(const u16x8*)(x + (size_t)s2 * K + c);
        u16x8 xd = *(const u16x8*)(x + (size_t)s3 * K + c);
        u16x8 ra = *(const u16x8*)(relb + (size_t)t0 * K + c);
        u16x8 rb = *(const u16x8*)(relb + (size_t)t1 * K + c);
        u16x8 rc = *(const u16x8*)(relb + (size_t)t2 * K + c);
        u16x8 rd = *(const u16x8*)(relb + (size_t)t3 * K + c);
#pragma unroll
        for (int i = 0; i < 8; ++i)
            acc[i] += n0 * bf2f(xa[i]) * bf2f(ra[i]) + n1 * bf2f(xb[i]) * bf2f(rb[i])
                    + n2 * bf2f(xc[i]) * bf2f(rc[i]) + n3 * bf2f(xd[i]) * bf2f(rd[i]);
    }
    for (; e < e1; ++e) {
        int s0 = cs[e], t0 = cet[e]; float n0 = cn[e];
        u16x8 xa = *(const u16x8*)(x + (size_t)s0 * K + c);
        u16x8 ra = *(const u16x8*)(relb + (size_t)t0 * K + c);
#pragma unroll
        for (int i = 0; i < 8; ++i) acc[i] += n0 * bf2f(xa[i]) * bf2f(ra[i]);
    }
    u16x8 o;
#pragma unroll
    for (int i = 0; i < 8; ++i) o[i] = f2bf(acc[i]);
    *(u16x8*)(agg + (size_t)node * K + c) = o;
}

// ---- async stage of one 16-row x 32-k chunk into LDS (global_load_lds x16) ----
__device__ __forceinline__ void stage16(const u16* __restrict__ src, int baseRow,
                                        int K, int kk, u16* lds, int chunk, int lane) {
    int row = chunk * 16 + (lane >> 2);
    int ks  = (lane & 3) ^ ((lane >> 2) & 3);
    const u16* g = src + (size_t)(baseRow + row) * K + kk + ks * 8;
    __builtin_amdgcn_global_load_lds((const __attribute__((address_space(1))) void*)g,
                                     (__attribute__((address_space(3))) void*)(lds + chunk * 512),
                                     16, 0, 0);
}

// ---- fused 3-segment MFMA GEMM, 128x64 tile (grid 1024 = 4 blocks/CU) ----
// hb = bf16((A1@W1t + A2@W2t + A3@W3t)/3 + bias); bnsums += per-col {sum, sumsq}
template <int K>
__global__ __launch_bounds__(256) void k_gemm_mfma(
    const u16* __restrict__ A1, const u16* __restrict__ A2, const u16* __restrict__ A3,
    const u16* __restrict__ W1, const u16* __restrict__ W2, const u16* __restrict__ W3,
    const float* __restrict__ bias, u16* __restrict__ hb, float* __restrict__ bnsums) {
    __shared__ u16 As_s[2][128 * 32];
    __shared__ u16 Ws_s[2][64 * 32];
    const int tid = threadIdx.x;
    const int wave = tid >> 6, lane = tid & 63;
    const int q = lane >> 4, r = lane & 15;
    const int rowBlk = blockIdx.x * 128;
    const int colBlk = blockIdx.y * 64;
    const int rowBase = rowBlk + (wave & 1) * 64;
    const int colSub  = (wave >> 1) * 32;

    f32x4 zero = {0.f, 0.f, 0.f, 0.f};
    f32x4 acc[4][2];
#pragma unroll
    for (int i = 0; i < 4; ++i)
#pragma unroll
        for (int j = 0; j < 2; ++j) acc[i][j] = zero;

    const u16* As[3] = {A1, A2, A3};
    const u16* Ws[3] = {W1, W2, W3};
    constexpr int SPS = K / 32;
    constexpr int TOT = 3 * SPS;

    // prologue: A 8 chunks (2/wave), W 4 chunks (1/wave)
    stage16(As[0], rowBlk, K, 0, As_s[0], 2 * wave, lane);
    stage16(As[0], rowBlk, K, 0, As_s[0], 2 * wave + 1, lane);
    stage16(Ws[0], colBlk, K, 0, Ws_s[0], wave, lane);

    const int sw = (q ^ (r & 3)) * 8;   // matches the stage-side k-slot permutation
    for (int s = 0; s < TOT; ++s) {
        __syncthreads();
        if (s + 1 < TOT) {
            int seg = (s + 1) / SPS;
            int kk  = ((s + 1) % SPS) * 32;
            stage16(As[seg], rowBlk, K, kk, As_s[(s + 1) & 1], 2 * wave, lane);
            stage16(As[seg], rowBlk, K, kk, As_s[(s + 1) & 1], 2 * wave + 1, lane);
            stage16(Ws[seg], colBlk, K, kk, Ws_s[(s + 1) & 1], wave, lane);
        }
        const u16* al = As_s[s & 1] + (wave & 1) * 64 * 32;
        const u16* wl = Ws_s[s & 1] + colSub * 32;
        bf16x8 a[4], b[2];
#pragma unroll
        for (int t = 0; t < 4; ++t) a[t] = *(const bf16x8*)(al + (t * 16 + r) * 32 + sw);
#pragma unroll
        for (int t = 0; t < 2; ++t) b[t] = *(const bf16x8*)(wl + (t * 16 + r) * 32 + sw);
#pragma unroll
        for (int tm = 0; tm < 4; ++tm)
#pragma unroll
            for (int tn = 0; tn < 2; ++tn)
                acc[tm][tn] = __builtin_amdgcn_mfma_f32_16x16x32_bf16(
                    a[tm], b[tn], acc[tm][tn], 0, 0, 0);
    }

    // epilogue: bf16 store + per-column partial BN stats
#pragma unroll
    for (int tn = 0; tn < 2; ++tn) {
        int col = colBlk + colSub + tn * 16 + r;
        float bv = bias[col];
        float sv = 0.f, qv = 0.f;
#pragma unroll
        for (int tm = 0; tm < 4; ++tm) {
#pragma unroll
            for (int reg = 0; reg < 4; ++reg) {
                int row = rowBase + tm * 16 + q * 4 + reg;
                float v = acc[tm][tn][reg] * (1.0f / 3.0f) + bv;
                hb[(size_t)row * 256 + col] = f2bf(v);
                sv += v; qv += v * v;
            }
        }
        sv += __shfl_xor(sv, 16); sv += __shfl_xor(sv, 32);
        qv += __shfl_xor(qv, 16); qv += __shfl_xor(qv, 32);
        if (q == 0) {
            atomicAdd(&bnsums[col], sv);
            atomicAdd(&bnsums[256 + col], qv);
        }
    }
}

// ---- small f32 GEMM for relation chain: C = A @ W, plus bf16 copy Cb ----
__global__ __launch_bounds__(256) void k_gemm_rel(
    const float* __restrict__ A, const float* __restrict__ W,
    float* __restrict__ C, u16* __restrict__ Cb, int M, int K) {
    __shared__ float As[16][68];
    __shared__ float Wshm[16][68];
    const int tid = threadIdx.x;
    const int tx = tid & 15, ty = tid >> 4;
    const int arow = tid >> 2;
    const int akc  = (tid & 3) << 2;
    const int wk   = tid >> 4;
    const int wn0  = (tid & 15) << 2;
    const int rowBase = blockIdx.x << 6;
    const int colBase = blockIdx.y << 6;
    float acc[4][4] = {};
    for (int k0 = 0; k0 < K; k0 += 16) {
        float4 av = make_float4(0.f, 0.f, 0.f, 0.f);
        int rr = rowBase + arow;
        if (rr < M) av = *(const float4*)(A + (size_t)rr * K + k0 + akc);
        As[akc + 0][arow] = av.x;
        As[akc + 1][arow] = av.y;
        As[akc + 2][arow] = av.z;
        As[akc + 3][arow] = av.w;
        float4 wv = *(const float4*)(W + (size_t)(k0 + wk) * D2 + colBase + wn0);
        Wshm[wk][wn0 + 0] = wv.x;
        Wshm[wk][wn0 + 1] = wv.y;
        Wshm[wk][wn0 + 2] = wv.z;
        Wshm[wk][wn0 + 3] = wv.w;
        __syncthreads();
#pragma unroll
        for (int kk = 0; kk < 16; ++kk) {
            float a0 = As[kk][(ty << 2) + 0], a1 = As[kk][(ty << 2) + 1];
            float a2 = As[kk][(ty << 2) + 2], a3 = As[kk][(ty << 2) + 3];
            float w0 = Wshm[kk][(tx << 2) + 0], w1 = Wshm[kk][(tx << 2) + 1];
            float w2 = Wshm[kk][(tx << 2) + 2], w3 = Wshm[kk][(tx << 2) + 3];
            acc[0][0] += a0 * w0; acc[0][1] += a0 * w1; acc[0][2] += a0 * w2; acc[0][3] += a0 * w3;
            acc[1][0] += a1 * w0; acc[1][1] += a1 * w1; acc[1][2] += a1 * w2; acc[1][3] += a1 * w3;
            acc[2][0] += a2 * w0; acc[2][1] += a2 * w1; acc[2][2] += a2 * w2; acc[2][3] += a2 * w3;
            acc[3][0] += a3 * w0; acc[3][1] += a3 * w1; acc[3][2] += a3 * w2; acc[3][3] += a3 * w3;
        }
        __syncthreads();
    }
#pragma unroll
    for (int i = 0; i < 4; ++i) {
        int rr = rowBase + (ty << 2) + i;
        if (rr >= M) continue;
        float* cp = C + (size_t)rr * D2 + colBase + (tx << 2);
        u16* cb = Cb + (size_t)rr * D2 + colBase + (tx << 2);
        cp[0] = acc[i][0]; cp[1] = acc[i][1]; cp[2] = acc[i][2]; cp[3] = acc[i][3];
        cb[0] = f2bf(acc[i][0]); cb[1] = f2bf(acc[i][1]);
        cb[2] = f2bf(acc[i][2]); cb[3] = f2bf(acc[i][3]);
    }
}

// ---- BN apply + ReLU from bf16 h, 8 elems/thread, emit bf16 x ----
__global__ void k_bnapply(const u16x8* __restrict__ hb8, const float* __restrict__ sums,
                          const float* __restrict__ gamma, const float* __restrict__ beta,
                          u16x8* __restrict__ xb8) {
    int idx = blockIdx.x * blockDim.x + threadIdx.x;
    int f0 = (idx & 31) << 3;
    u16x8 v = hb8[idx];
    u16x8 o;
#pragma unroll
    for (int i = 0; i < 8; ++i) {
        int f = f0 + i;
        float mean = sums[f] * (1.0f / NN);
        float var  = sums[256 + f] * (1.0f / NN) - mean * mean;
        float inv  = 1.0f / sqrtf(var + 1e-5f);
        float t = (bf2f(v[i]) - mean) * inv * gamma[f] + beta[f];
        o[i] = f2bf(t > 0.f ? t : 0.f);
    }
    xb8[idx] = o;
}

// ---- head features ----
__global__ void k_feats(const u16* __restrict__ x, const float* __restrict__ rel,
                        const int* __restrict__ rel_labels, float* __restrict__ feats) {
    int g = blockIdx.x, f = threadIdx.x;
    const u16* xg = x + (size_t)g * NPGN * D2;
    float s = 0.f;
#pragma unroll 8
    for (int n = 0; n < NPGN; ++n) s += bf2f(xg[(size_t)n * D2 + f]);
    float* fg = feats + (size_t)g * 1024;
    fg[f]       = s * (1.0f / NPGN);
    fg[256 + f] = rel[(size_t)rel_labels[g] * D2 + f];
    fg[512 + f] = bf2f(xg[f]);
    fg[768 + f] = bf2f(xg[D2 + f]);
}

// ---- final linear ----
__global__ void k_head(const float* __restrict__ feats, const float* __restrict__ lw,
                       const float* __restrict__ lb, float* __restrict__ out) {
    int g = blockIdx.x, t = threadIdx.x;
    __shared__ float s0[256], s1[256];
    float a0 = 0.f, a1 = 0.f;
#pragma unroll
    for (int j = 0; j < 4; ++j) {
        int k = t * 4 + j;
        float fv = feats[(size_t)g * 1024 + k];
        a0 += fv * lw[k * 2 + 0];
        a1 += fv * lw[k * 2 + 1];
    }
    s0[t] = a0; s1[t] = a1;
    __syncthreads();
    for (int s = 128; s > 0; s >>= 1) {
        if (t < s) { s0[t] += s0[t + s]; s1[t] += s1[t + s]; }
        __syncthreads();
    }
    if (t == 0) {
        out[g * 2 + 0] = s0[0] + lb[0];
        out[g * 2 + 1] = s1[0] + lb[1];
    }
}

extern "C" void kernel_launch(void* const* d_in, const int* in_sizes, int n_in,
                              void* d_out, int out_size, void* d_ws, size_t ws_size,
                              hipStream_t stream) {
    const float* x0   = (const float*)d_in[0];
    const float* rel0 = (const float*)d_in[1];
    const int* edge_index = (const int*)d_in[20];
    const int* edge_type  = (const int*)d_in[21];
    const int* rel_labels = (const int*)d_in[23];
    float* out = (float*)d_out;

    // ---- workspace carve (~70 MB) ----
    float* ws = (float*)d_ws;
    float* relA  = ws;                              // RR*256
    float* relB  = relA + (size_t)RR * 256;         // RR*256
    float* dinv_in  = relB + (size_t)RR * 256;      // NN
    float* dinv_out = dinv_in + NN;                 // NN
    float* cnorm_in  = dinv_out + NN;               // EH
    float* cnorm_out = cnorm_in + EH;               // EH
    float* bnsums    = cnorm_out + EH;              // 512
    float* feats     = bnsums + 512;                // GG*1024
    int* csrc_in  = (int*)(feats + GG * 1024);      // EH
    int* cet_in   = csrc_in + EH;                   // EH
    int* csrc_out = cet_in + EH;                    // EH
    int* cet_out  = csrc_out + EH;                  // EH
    int* off_in   = cet_out + EH;                   // NN+8
    int* off_out  = off_in + NN + 8;                // NN+8
    int* hs_in    = off_out + NN + 8;               // NN  -- zeroed region start
    int* hs_out   = hs_in + NN;                     // NN
    int* hd_in    = hs_out + NN;                    // NN
    int* hd_out   = hd_in + NN;                     // NN
    int* cur_in   = hd_out + NN;                    // NN
    int* cur_out  = cur_in + NN;                    // NN -- zeroed region end
    u16* xbf0 = (u16*)(cur_out + NN);               // NN*128 bf16
    u16* xbfA = xbf0 + (size_t)NN * 128;            // NN*256 bf16
    u16* aggI = xbfA + (size_t)NN * 256;            // NN*256 bf16
    u16* aggO = aggI + (size_t)NN * 256;            // NN*256 bf16
    u16* hb   = aggO + (size_t)NN * 256;            // NN*256 bf16 (pre-BN h)
    u16* wt0  = hb + (size_t)NN * 256;              // 3*256*128
    u16* wtS  = wt0 + 3 * 256 * 128;                // 12*256*256
    u16* relbf = wtS + 12 * 65536;                  // RR*256 bf16

    // ---- CSR build + conversions + weight prep (once per launch) ----
    hipMemsetAsync(hs_in, 0, 6 * NN * sizeof(int), stream);
    k_hist<<<ET / 256, 256, 0, stream>>>(edge_index, hs_in, hs_out, hd_in, hd_out);
    k_dinv<<<NN / 256, 256, 0, stream>>>(hs_in, hs_out, dinv_in, dinv_out);
    k_scan<<<1, 1024, 0, stream>>>(hd_in, off_in);
    k_scan<<<1, 1024, 0, stream>>>(hd_out, off_out);
    k_fill<<<EH / 256, 256, 0, stream>>>(edge_index, edge_type, dinv_in, off_in,
                                         cur_in, csrc_in, cet_in, cnorm_in, 0);
    k_fill<<<EH / 256, 256, 0, stream>>>(edge_index, edge_type, dinv_out, off_out,
                                         cur_out, csrc_out, cet_out, cnorm_out, EH);
    k_convx<<<(NN * D1) / 256, 256, 0, stream>>>(x0, xbf0, NN * D1);
    k_convx<<<(RR * D1 + 255) / 256, 256, 0, stream>>>(rel0, relbf, RR * D1);
    k_prepw<<<(3 * D1 * 256) / 256, 256, 0, stream>>>(
        (const float*)d_in[2], (const float*)d_in[3], (const float*)d_in[4],
        (const float*)d_in[6], wt0, wt0 + 256 * D1, wt0 + 2 * 256 * D1, D1, 1);
    k_prepw<<<(3 * 4 * D2 * 256) / 256, 256, 0, stream>>>(
        (const float*)d_in[10], (const float*)d_in[11], (const float*)d_in[12],
        (const float*)d_in[14], wtS, wtS + 4 * 65536, wtS + 8 * 65536, D2, 4);

    const float* rc = rel0; float* rn = relA;

    for (int l = 0; l < 5; ++l) {
        const int K = (l == 0) ? D1 : D2;
        const u16* xb = (l == 0) ? xbf0 : xbfA;
        const u16 *WiT, *WoT, *WlT;
        const float *Wr, *bias, *gamma, *beta;
        if (l == 0) {
            WiT = wt0; WoT = wt0 + 256 * D1; WlT = wt0 + 2 * 256 * D1;
            Wr = (const float*)d_in[5];
            bias  = (const float*)d_in[7];
            gamma = (const float*)d_in[8];
            beta  = (const float*)d_in[9];
        } else {
            int m = l - 1;
            WiT = wtS + (size_t)m * 65536;
            WoT = wtS + (size_t)(4 + m) * 65536;
            WlT = wtS + (size_t)(8 + m) * 65536;
            Wr = (const float*)d_in[13] + (size_t)m * D2 * D2;
            bias  = (const float*)d_in[15] + (size_t)m * D2;
            gamma = (const float*)d_in[16] + (size_t)m * D2;
            beta  = (const float*)d_in[17] + (size_t)m * D2;
        }

        // feature-phase tiled gather, both dirs (zeroes bnsums too)
        dim3 ggr(NN / 32, 2, K / 64);
        if (K == D1) k_gather2<D1><<<ggr, 256, 0, stream>>>(xb, relbf, csrc_in, cet_in,
            cnorm_in, off_in, csrc_out, cet_out, cnorm_out, off_out, aggI, aggO, bnsums);
        else         k_gather2<D2><<<ggr, 256, 0, stream>>>(xb, relbf, csrc_in, cet_in,
            cnorm_in, off_in, csrc_out, cet_out, cnorm_out, off_out, aggI, aggO, bnsums);
        // fused 3-segment MFMA GEMM (128x64 tiles, 4 blocks/CU) + BN stats, bf16 h out
        dim3 ggrid(NN / 128, 4);
        if (K == D1) k_gemm_mfma<D1><<<ggrid, 256, 0, stream>>>(aggI, aggO, xb, WiT, WoT, WlT, bias, hb, bnsums);
        else         k_gemm_mfma<D2><<<ggrid, 256, 0, stream>>>(aggI, aggO, xb, WiT, WoT, WlT, bias, hb, bnsums);
        // BN apply + relu -> bf16 x
        k_bnapply<<<(NN * 256 / 8) / 256, 256, 0, stream>>>((const u16x8*)hb, bnsums,
                                                            gamma, beta, (u16x8*)xbfA);
        // relation transform (f32 chain + bf16 copy for gathers)
        k_gemm_rel<<<dim3(4, 4), 256, 0, stream>>>(rc, Wr, rn, relbf, RR, K);
        const float* nr = rn;
        rn = (l == 0) ? relB : (float*)rc;
        rc = nr;
    }

    k_feats<<<GG, 256, 0, stream>>>(xbfA, rc, rel_labels, feats);
    k_head<<<GG, 256, 0, stream>>>(feats, (const float*)d_in[18],
                                   (const float*)d_in[19], out);
}

// Round 11
// 814.387 us; speedup vs baseline: 1.1074x; 1.1074x over previous
//
#include <hip/hip_runtime.h>

#define NN 32768      // total nodes
#define GG 256        // graphs
#define NPGN 128      // nodes per graph
#define ET 524288     // total directed edges
#define EH 262144     // edges per direction
#define D1 128        // input feature dim
#define D2 256        // hidden dim
#define RR 200        // relations

typedef unsigned short u16;
typedef __attribute__((ext_vector_type(8))) short bf16x8;   // MFMA A/B frag (4 VGPR)
typedef __attribute__((ext_vector_type(4))) float f32x4;    // MFMA C/D frag
typedef __attribute__((ext_vector_type(8))) unsigned short u16x8;

__device__ __forceinline__ float bf2f(u16 u) {
    union { unsigned int i; float f; } v; v.i = ((unsigned int)u) << 16; return v.f;
}
__device__ __forceinline__ u16 f2bf(float f) {
    union { unsigned int i; float f; } v; v.f = f;
    unsigned int x = v.i;
    return (u16)((x + 0x7fffu + ((x >> 16) & 1u)) >> 16);   // RNE
}

// ---- histograms: by-src (for norm) and by-dst (for CSR) per direction ----
__global__ void k_hist(const int* __restrict__ ei, int* __restrict__ hs_in,
                       int* __restrict__ hs_out, int* __restrict__ hd_in,
                       int* __restrict__ hd_out) {
    int e = blockIdx.x * blockDim.x + threadIdx.x;
    if (e >= ET) return;
    int s = ei[e], d = ei[ET + e];
    if (e < EH) { atomicAdd(&hs_in[s], 1);  atomicAdd(&hd_in[d], 1); }
    else        { atomicAdd(&hs_out[s], 1); atomicAdd(&hd_out[d], 1); }
}

__global__ void k_dinv(const int* __restrict__ hs_in, const int* __restrict__ hs_out,
                       float* __restrict__ dinv_in, float* __restrict__ dinv_out) {
    int n = blockIdx.x * blockDim.x + threadIdx.x;
    if (n >= NN) return;
    int a = hs_in[n], b = hs_out[n];
    dinv_in[n]  = a > 0 ? rsqrtf((float)a) : 0.f;
    dinv_out[n] = b > 0 ? rsqrtf((float)b) : 0.f;
}

// ---- exclusive scan of 32768 ints, single block of 1024 ----
__global__ __launch_bounds__(1024) void k_scan(const int* __restrict__ hist,
                                               int* __restrict__ off) {
    __shared__ int lds[1024];
    int t = threadIdx.x;
    int base = t * 32;
    int loc[32];
    int s = 0;
#pragma unroll
    for (int i = 0; i < 32; ++i) { loc[i] = s; s += hist[base + i]; }
    lds[t] = s;
    int tot = s;
    __syncthreads();
    for (int st = 1; st < 1024; st <<= 1) {
        int v = (t >= st) ? lds[t - st] : 0;
        __syncthreads();
        lds[t] += v;
        __syncthreads();
    }
    int excl = lds[t] - tot;
#pragma unroll
    for (int i = 0; i < 32; ++i) off[base + i] = excl + loc[i];
    if (t == 1023) off[NN] = lds[1023];
}

// ---- fill CSR slots (dst-sorted); norm folded in ----
__global__ void k_fill(const int* __restrict__ ei, const int* __restrict__ et,
                       const float* __restrict__ dinv, const int* __restrict__ off,
                       int* __restrict__ cur, int* __restrict__ c_src,
                       int* __restrict__ c_et, float* __restrict__ c_norm, int eoff) {
    int e = blockIdx.x * blockDim.x + threadIdx.x;
    if (e >= EH) return;
    int s = ei[eoff + e], d = ei[ET + eoff + e], t = et[eoff + e];
    int slot = off[d] + atomicAdd(&cur[d], 1);
    c_src[slot] = s;
    c_et[slot] = t;
    c_norm[slot] = dinv[s] * dinv[d];
}

// ---- f32 -> bf16 ----
__global__ void k_convx(const float* __restrict__ in, u16* __restrict__ out, int n) {
    int i = blockIdx.x * blockDim.x + threadIdx.x;
    if (i < n) out[i] = f2bf(in[i]);
}

// ---- weight prep via LDS 32x32 tile transpose (both sides coalesced) ----
// Wt[l][n][k] = bf16(W[l][k][n] * (fam==2 ? lr[l][k] : 1))
__global__ __launch_bounds__(256) void k_prepw(
    const float* __restrict__ Wi, const float* __restrict__ Wo,
    const float* __restrict__ Wl, const float* __restrict__ lr,
    u16* __restrict__ WiT, u16* __restrict__ WoT, u16* __restrict__ WlT, int K) {
    __shared__ float tile[32][33];
    const int fam = blockIdx.z;
    const int l = blockIdx.y;
    const int ntiles_n = 256 / 32;
    const int k0 = (blockIdx.x / ntiles_n) * 32;
    const int n0 = (blockIdx.x % ntiles_n) * 32;
    const float* src = fam == 0 ? Wi : fam == 1 ? Wo : Wl;
    u16* dst = fam == 0 ? WiT : fam == 1 ? WoT : WlT;
    const int tn = threadIdx.x & 31, tk = threadIdx.x >> 5;   // load: n fast
#pragma unroll
    for (int j = 0; j < 4; ++j) {
        int k = k0 + tk + j * 8;
        tile[tk + j * 8][tn] = src[((size_t)l * K + k) * 256 + n0 + tn];
    }
    __syncthreads();
    const int tk2 = threadIdx.x & 31, tn2 = threadIdx.x >> 5; // store: k fast
    float scale = 1.0f;
    if (fam == 2) scale = lr[(size_t)l * K + k0 + tk2];
#pragma unroll
    for (int j = 0; j < 4; ++j) {
        int n = n0 + tn2 + j * 8;
        dst[((size_t)l * 256 + n) * K + k0 + tk2] = f2bf(tile[tk2][tn2 + j * 8] * scale);
    }
}

// ---- gather, both directions: K/8 lanes per node (16B frags), 4-edge unroll ----
// R8's measured-best form. Also zeroes bnsums (block 0) for the GEMM's BN stats.
template <int K>
__global__ __launch_bounds__(256) void k_gather2(
    const u16* __restrict__ x, const u16* __restrict__ relb,
    const int* __restrict__ csI, const int* __restrict__ cetI,
    const float* __restrict__ cnI, const int* __restrict__ offI,
    const int* __restrict__ csO, const int* __restrict__ cetO,
    const float* __restrict__ cnO, const int* __restrict__ offO,
    u16* __restrict__ aggI, u16* __restrict__ aggO, float* __restrict__ bnsums) {
    if (blockIdx.x == 0 && blockIdx.y == 0 && threadIdx.x < 128)
        ((float4*)bnsums)[threadIdx.x] = make_float4(0.f, 0.f, 0.f, 0.f);
    constexpr int LPN = K / 8;            // lanes per node
    constexpr int NPB = 256 / LPN;        // nodes per block
    const int dir = blockIdx.y;
    const int* __restrict__ cs  = dir ? csO : csI;
    const int* __restrict__ cet = dir ? cetO : cetI;
    const float* __restrict__ cn = dir ? cnO : cnI;
    const int* __restrict__ off = dir ? offO : offI;
    u16* __restrict__ agg = dir ? aggO : aggI;

    int node = blockIdx.x * NPB + (threadIdx.x / LPN);
    int lane = threadIdx.x % LPN;
    int c = lane * 8;
    int e0 = off[node], e1 = off[node + 1];
    float acc[8] = {};
    int e = e0;
    for (; e + 4 <= e1; e += 4) {
        int s0 = cs[e],  s1 = cs[e + 1],  s2 = cs[e + 2],  s3 = cs[e + 3];
        int t0 = cet[e], t1 = cet[e + 1], t2 = cet[e + 2], t3 = cet[e + 3];
        float n0 = cn[e], n1 = cn[e + 1], n2 = cn[e + 2], n3 = cn[e + 3];
        u16x8 xa = *(const u16x8*)(x + (size_t)s0 * K + c);
        u16x8 xb = *(const u16x8*)(x + (size_t)s1 * K + c);
        u16x8 xc = *(const u16x8*)(x + (size_t)s2 * K + c);
        u16x8 xd = *(const u16x8*)(x + (size_t)s3 * K + c);
        u16x8 ra = *(const u16x8*)(relb + (size_t)t0 * K + c);
        u16x8 rb = *(const u16x8*)(relb + (size_t)t1 * K + c);
        u16x8 rc = *(const u16x8*)(relb + (size_t)t2 * K + c);
        u16x8 rd = *(const u16x8*)(relb + (size_t)t3 * K + c);
#pragma unroll
        for (int i = 0; i < 8; ++i)
            acc[i] += n0 * bf2f(xa[i]) * bf2f(ra[i]) + n1 * bf2f(xb[i]) * bf2f(rb[i])
                    + n2 * bf2f(xc[i]) * bf2f(rc[i]) + n3 * bf2f(xd[i]) * bf2f(rd[i]);
    }
    for (; e < e1; ++e) {
        int s0 = cs[e], t0 = cet[e]; float n0 = cn[e];
        u16x8 xa = *(const u16x8*)(x + (size_t)s0 * K + c);
        u16x8 ra = *(const u16x8*)(relb + (size_t)t0 * K + c);
#pragma unroll
        for (int i = 0; i < 8; ++i) acc[i] += n0 * bf2f(xa[i]) * bf2f(ra[i]);
    }
    u16x8 o;
#pragma unroll
    for (int i = 0; i < 8; ++i) o[i] = f2bf(acc[i]);
    *(u16x8*)(agg + (size_t)node * K + c) = o;
}

// ---- async stage of one 16-row x 32-k chunk into LDS (global_load_lds x16) ----
__device__ __forceinline__ void stage16(const u16* __restrict__ src, int baseRow,
                                        int K, int kk, u16* lds, int chunk, int lane) {
    int row = chunk * 16 + (lane >> 2);
    int ks  = (lane & 3) ^ ((lane >> 2) & 3);
    const u16* g = src + (size_t)(baseRow + row) * K + kk + ks * 8;
    __builtin_amdgcn_global_load_lds((const __attribute__((address_space(1))) void*)g,
                                     (__attribute__((address_space(3))) void*)(lds + chunk * 512),
                                     16, 0, 0);
}

// ---- fused 3-segment MFMA GEMM, 128x64 tile (grid 1024 = 4 blocks/CU) ----
// hb = bf16((A1@W1t + A2@W2t + A3@W3t)/3 + bias); bnsums += per-col {sum, sumsq}
template <int K>
__global__ __launch_bounds__(256) void k_gemm_mfma(
    const u16* __restrict__ A1, const u16* __restrict__ A2, const u16* __restrict__ A3,
    const u16* __restrict__ W1, const u16* __restrict__ W2, const u16* __restrict__ W3,
    const float* __restrict__ bias, u16* __restrict__ hb, float* __restrict__ bnsums) {
    __shared__ u16 As_s[2][128 * 32];
    __shared__ u16 Ws_s[2][64 * 32];
    const int tid = threadIdx.x;
    const int wave = tid >> 6, lane = tid & 63;
    const int q = lane >> 4, r = lane & 15;
    const int rowBlk = blockIdx.x * 128;
    const int colBlk = blockIdx.y * 64;
    const int rowBase = rowBlk + (wave & 1) * 64;
    const int colSub  = (wave >> 1) * 32;

    f32x4 zero = {0.f, 0.f, 0.f, 0.f};
    f32x4 acc[4][2];
#pragma unroll
    for (int i = 0; i < 4; ++i)
#pragma unroll
        for (int j = 0; j < 2; ++j) acc[i][j] = zero;

    const u16* As[3] = {A1, A2, A3};
    const u16* Ws[3] = {W1, W2, W3};
    constexpr int SPS = K / 32;
    constexpr int TOT = 3 * SPS;

    // prologue: A 8 chunks (2/wave), W 4 chunks (1/wave)
    stage16(As[0], rowBlk, K, 0, As_s[0], 2 * wave, lane);
    stage16(As[0], rowBlk, K, 0, As_s[0], 2 * wave + 1, lane);
    stage16(Ws[0], colBlk, K, 0, Ws_s[0], wave, lane);

    const int sw = (q ^ (r & 3)) * 8;   // matches the stage-side k-slot permutation
    for (int s = 0; s < TOT; ++s) {
        __syncthreads();
        if (s + 1 < TOT) {
            int seg = (s + 1) / SPS;
            int kk  = ((s + 1) % SPS) * 32;
            stage16(As[seg], rowBlk, K, kk, As_s[(s + 1) & 1], 2 * wave, lane);
            stage16(As[seg], rowBlk, K, kk, As_s[(s + 1) & 1], 2 * wave + 1, lane);
            stage16(Ws[seg], colBlk, K, kk, Ws_s[(s + 1) & 1], wave, lane);
        }
        const u16* al = As_s[s & 1] + (wave & 1) * 64 * 32;
        const u16* wl = Ws_s[s & 1] + colSub * 32;
        bf16x8 a[4], b[2];
#pragma unroll
        for (int t = 0; t < 4; ++t) a[t] = *(const bf16x8*)(al + (t * 16 + r) * 32 + sw);
#pragma unroll
        for (int t = 0; t < 2; ++t) b[t] = *(const bf16x8*)(wl + (t * 16 + r) * 32 + sw);
#pragma unroll
        for (int tm = 0; tm < 4; ++tm)
#pragma unroll
            for (int tn = 0; tn < 2; ++tn)
                acc[tm][tn] = __builtin_amdgcn_mfma_f32_16x16x32_bf16(
                    a[tm], b[tn], acc[tm][tn], 0, 0, 0);
    }

    // epilogue: bf16 store + per-column partial BN stats
#pragma unroll
    for (int tn = 0; tn < 2; ++tn) {
        int col = colBlk + colSub + tn * 16 + r;
        float bv = bias[col];
        float sv = 0.f, qv = 0.f;
#pragma unroll
        for (int tm = 0; tm < 4; ++tm) {
#pragma unroll
            for (int reg = 0; reg < 4; ++reg) {
                int row = rowBase + tm * 16 + q * 4 + reg;
                float v = acc[tm][tn][reg] * (1.0f / 3.0f) + bv;
                hb[(size_t)row * 256 + col] = f2bf(v);
                sv += v; qv += v * v;
            }
        }
        sv += __shfl_xor(sv, 16); sv += __shfl_xor(sv, 32);
        qv += __shfl_xor(qv, 16); qv += __shfl_xor(qv, 32);
        if (q == 0) {
            atomicAdd(&bnsums[col], sv);
            atomicAdd(&bnsums[256 + col], qv);
        }
    }
}

// ---- small f32 GEMM for relation chain: C = A @ W, plus bf16 copy Cb ----
__global__ __launch_bounds__(256) void k_gemm_rel(
    const float* __restrict__ A, const float* __restrict__ W,
    float* __restrict__ C, u16* __restrict__ Cb, int M, int K) {
    __shared__ float As[16][68];
    __shared__ float Wshm[16][68];
    const int tid = threadIdx.x;
    const int tx = tid & 15, ty = tid >> 4;
    const int arow = tid >> 2;
    const int akc  = (tid & 3) << 2;
    const int wk   = tid >> 4;
    const int wn0  = (tid & 15) << 2;
    const int rowBase = blockIdx.x << 6;
    const int colBase = blockIdx.y << 6;
    float acc[4][4] = {};
    for (int k0 = 0; k0 < K; k0 += 16) {
        float4 av = make_float4(0.f, 0.f, 0.f, 0.f);
        int rr = rowBase + arow;
        if (rr < M) av = *(const float4*)(A + (size_t)rr * K + k0 + akc);
        As[akc + 0][arow] = av.x;
        As[akc + 1][arow] = av.y;
        As[akc + 2][arow] = av.z;
        As[akc + 3][arow] = av.w;
        float4 wv = *(const float4*)(W + (size_t)(k0 + wk) * D2 + colBase + wn0);
        Wshm[wk][wn0 + 0] = wv.x;
        Wshm[wk][wn0 + 1] = wv.y;
        Wshm[wk][wn0 + 2] = wv.z;
        Wshm[wk][wn0 + 3] = wv.w;
        __syncthreads();
#pragma unroll
        for (int kk = 0; kk < 16; ++kk) {
            float a0 = As[kk][(ty << 2) + 0], a1 = As[kk][(ty << 2) + 1];
            float a2 = As[kk][(ty << 2) + 2], a3 = As[kk][(ty << 2) + 3];
            float w0 = Wshm[kk][(tx << 2) + 0], w1 = Wshm[kk][(tx << 2) + 1];
            float w2 = Wshm[kk][(tx << 2) + 2], w3 = Wshm[kk][(tx << 2) + 3];
            acc[0][0] += a0 * w0; acc[0][1] += a0 * w1; acc[0][2] += a0 * w2; acc[0][3] += a0 * w3;
            acc[1][0] += a1 * w0; acc[1][1] += a1 * w1; acc[1][2] += a1 * w2; acc[1][3] += a1 * w3;
            acc[2][0] += a2 * w0; acc[2][1] += a2 * w1; acc[2][2] += a2 * w2; acc[2][3] += a2 * w3;
            acc[3][0] += a3 * w0; acc[3][1] += a3 * w1; acc[3][2] += a3 * w2; acc[3][3] += a3 * w3;
        }
        __syncthreads();
    }
#pragma unroll
    for (int i = 0; i < 4; ++i) {
        int rr = rowBase + (ty << 2) + i;
        if (rr >= M) continue;
        float* cp = C + (size_t)rr * D2 + colBase + (tx << 2);
        u16* cb = Cb + (size_t)rr * D2 + colBase + (tx << 2);
        cp[0] = acc[i][0]; cp[1] = acc[i][1]; cp[2] = acc[i][2]; cp[3] = acc[i][3];
        cb[0] = f2bf(acc[i][0]); cb[1] = f2bf(acc[i][1]);
        cb[2] = f2bf(acc[i][2]); cb[3] = f2bf(acc[i][3]);
    }
}

// ---- BN apply + ReLU from bf16 h, 8 elems/thread, emit bf16 x ----
__global__ void k_bnapply(const u16x8* __restrict__ hb8, const float* __restrict__ sums,
                          const float* __restrict__ gamma, const float* __restrict__ beta,
                          u16x8* __restrict__ xb8) {
    int idx = blockIdx.x * blockDim.x + threadIdx.x;
    int f0 = (idx & 31) << 3;
    u16x8 v = hb8[idx];
    u16x8 o;
#pragma unroll
    for (int i = 0; i < 8; ++i) {
        int f = f0 + i;
        float mean = sums[f] * (1.0f / NN);
        float var  = sums[256 + f] * (1.0f / NN) - mean * mean;
        float inv  = 1.0f / sqrtf(var + 1e-5f);
        float t = (bf2f(v[i]) - mean) * inv * gamma[f] + beta[f];
        o[i] = f2bf(t > 0.f ? t : 0.f);
    }
    xb8[idx] = o;
}

// ---- head features ----
__global__ void k_feats(const u16* __restrict__ x, const float* __restrict__ rel,
                        const int* __restrict__ rel_labels, float* __restrict__ feats) {
    int g = blockIdx.x, f = threadIdx.x;
    const u16* xg = x + (size_t)g * NPGN * D2;
    float s = 0.f;
#pragma unroll 8
    for (int n = 0; n < NPGN; ++n) s += bf2f(xg[(size_t)n * D2 + f]);
    float* fg = feats + (size_t)g * 1024;
    fg[f]       = s * (1.0f / NPGN);
    fg[256 + f] = rel[(size_t)rel_labels[g] * D2 + f];
    fg[512 + f] = bf2f(xg[f]);
    fg[768 + f] = bf2f(xg[D2 + f]);
}

// ---- final linear ----
__global__ void k_head(const float* __restrict__ feats, const float* __restrict__ lw,
                       const float* __restrict__ lb, float* __restrict__ out) {
    int g = blockIdx.x, t = threadIdx.x;
    __shared__ float s0[256], s1[256];
    float a0 = 0.f, a1 = 0.f;
#pragma unroll
    for (int j = 0; j < 4; ++j) {
        int k = t * 4 + j;
        float fv = feats[(size_t)g * 1024 + k];
        a0 += fv * lw[k * 2 + 0];
        a1 += fv * lw[k * 2 + 1];
    }
    s0[t] = a0; s1[t] = a1;
    __syncthreads();
    for (int s = 128; s > 0; s >>= 1) {
        if (t < s) { s0[t] += s0[t + s]; s1[t] += s1[t + s]; }
        __syncthreads();
    }
    if (t == 0) {
        out[g * 2 + 0] = s0[0] + lb[0];
        out[g * 2 + 1] = s1[0] + lb[1];
    }
}

extern "C" void kernel_launch(void* const* d_in, const int* in_sizes, int n_in,
                              void* d_out, int out_size, void* d_ws, size_t ws_size,
                              hipStream_t stream) {
    const float* x0   = (const float*)d_in[0];
    const float* rel0 = (const float*)d_in[1];
    const int* edge_index = (const int*)d_in[20];
    const int* edge_type  = (const int*)d_in[21];
    const int* rel_labels = (const int*)d_in[23];
    float* out = (float*)d_out;

    // ---- workspace carve (~70 MB) ----
    float* ws = (float*)d_ws;
    float* relA  = ws;                              // RR*256
    float* relB  = relA + (size_t)RR * 256;         // RR*256
    float* dinv_in  = relB + (size_t)RR * 256;      // NN
    float* dinv_out = dinv_in + NN;                 // NN
    float* cnorm_in  = dinv_out + NN;               // EH
    float* cnorm_out = cnorm_in + EH;               // EH
    float* bnsums    = cnorm_out + EH;              // 512
    float* feats     = bnsums + 512;                // GG*1024
    int* csrc_in  = (int*)(feats + GG * 1024);      // EH
    int* cet_in   = csrc_in + EH;                   // EH
    int* csrc_out = cet_in + EH;                    // EH
    int* cet_out  = csrc_out + EH;                  // EH
    int* off_in   = cet_out + EH;                   // NN+8
    int* off_out  = off_in + NN + 8;                // NN+8
    int* hs_in    = off_out + NN + 8;               // NN  -- zeroed region start
    int* hs_out   = hs_in + NN;                     // NN
    int* hd_in    = hs_out + NN;                    // NN
    int* hd_out   = hd_in + NN;                     // NN
    int* cur_in   = hd_out + NN;                    // NN
    int* cur_out  = cur_in + NN;                    // NN -- zeroed region end
    u16* xbf0 = (u16*)(cur_out + NN);               // NN*128 bf16
    u16* xbfA = xbf0 + (size_t)NN * 128;            // NN*256 bf16
    u16* aggI = xbfA + (size_t)NN * 256;            // NN*256 bf16
    u16* aggO = aggI + (size_t)NN * 256;            // NN*256 bf16
    u16* hb   = aggO + (size_t)NN * 256;            // NN*256 bf16 (pre-BN h)
    u16* wt0  = hb + (size_t)NN * 256;              // 3*256*128
    u16* wtS  = wt0 + 3 * 256 * 128;                // 12*256*256
    u16* relbf = wtS + 12 * 65536;                  // RR*256 bf16

    // ---- CSR build + conversions + weight prep (once per launch) ----
    hipMemsetAsync(hs_in, 0, 6 * NN * sizeof(int), stream);
    k_hist<<<ET / 256, 256, 0, stream>>>(edge_index, hs_in, hs_out, hd_in, hd_out);
    k_dinv<<<NN / 256, 256, 0, stream>>>(hs_in, hs_out, dinv_in, dinv_out);
    k_scan<<<1, 1024, 0, stream>>>(hd_in, off_in);
    k_scan<<<1, 1024, 0, stream>>>(hd_out, off_out);
    k_fill<<<EH / 256, 256, 0, stream>>>(edge_index, edge_type, dinv_in, off_in,
                                         cur_in, csrc_in, cet_in, cnorm_in, 0);
    k_fill<<<EH / 256, 256, 0, stream>>>(edge_index, edge_type, dinv_out, off_out,
                                         cur_out, csrc_out, cet_out, cnorm_out, EH);
    k_convx<<<(NN * D1) / 256, 256, 0, stream>>>(x0, xbf0, NN * D1);
    k_convx<<<(RR * D1 + 255) / 256, 256, 0, stream>>>(rel0, relbf, RR * D1);
    {
        dim3 g0((D1 / 32) * 8, 1, 3);   // layer-0 weights: K=128
        k_prepw<<<g0, 256, 0, stream>>>(
            (const float*)d_in[2], (const float*)d_in[3], (const float*)d_in[4],
            (const float*)d_in[6], wt0, wt0 + 256 * D1, wt0 + 2 * 256 * D1, D1);
        dim3 gS((D2 / 32) * 8, 4, 3);   // stacked weights: K=256, L=4
        k_prepw<<<gS, 256, 0, stream>>>(
            (const float*)d_in[10], (const float*)d_in[11], (const float*)d_in[12],
            (const float*)d_in[14], wtS, wtS + 4 * 65536, wtS + 8 * 65536, D2);
    }

    const float* rc = rel0; float* rn = relA;

    for (int l = 0; l < 5; ++l) {
        const int K = (l == 0) ? D1 : D2;
        const u16* xb = (l == 0) ? xbf0 : xbfA;
        const u16 *WiT, *WoT, *WlT;
        const float *Wr, *bias, *gamma, *beta;
        if (l == 0) {
            WiT = wt0; WoT = wt0 + 256 * D1; WlT = wt0 + 2 * 256 * D1;
            Wr = (const float*)d_in[5];
            bias  = (const float*)d_in[7];
            gamma = (const float*)d_in[8];
            beta  = (const float*)d_in[9];
        } else {
            int m = l - 1;
            WiT = wtS + (size_t)m * 65536;
            WoT = wtS + (size_t)(4 + m) * 65536;
            WlT = wtS + (size_t)(8 + m) * 65536;
            Wr = (const float*)d_in[13] + (size_t)m * D2 * D2;
            bias  = (const float*)d_in[15] + (size_t)m * D2;
            gamma = (const float*)d_in[16] + (size_t)m * D2;
            beta  = (const float*)d_in[17] + (size_t)m * D2;
        }

        // both-direction gather into bf16 agg buffers (zeroes bnsums too)
        if (K == D1) {
            dim3 ggr(NN / 16, 2);
            k_gather2<D1><<<ggr, 256, 0, stream>>>(xb, relbf, csrc_in, cet_in,
                cnorm_in, off_in, csrc_out, cet_out, cnorm_out, off_out, aggI, aggO, bnsums);
        } else {
            dim3 ggr(NN / 8, 2);
            k_gather2<D2><<<ggr, 256, 0, stream>>>(xb, relbf, csrc_in, cet_in,
                cnorm_in, off_in, csrc_out, cet_out, cnorm_out, off_out, aggI, aggO, bnsums);
        }
        // fused 3-segment MFMA GEMM (128x64 tiles, 4 blocks/CU) + BN stats, bf16 h out
        dim3 ggrid(NN / 128, 4);
        if (K == D1) k_gemm_mfma<D1><<<ggrid, 256, 0, stream>>>(aggI, aggO, xb, WiT, WoT, WlT, bias, hb, bnsums);
        else         k_gemm_mfma<D2><<<ggrid, 256, 0, stream>>>(aggI, aggO, xb, WiT, WoT, WlT, bias, hb, bnsums);
        // BN apply + relu -> bf16 x
        k_bnapply<<<(NN * 256 / 8) / 256, 256, 0, stream>>>((const u16x8*)hb, bnsums,
                                                            gamma, beta, (u16x8*)xbfA);
        // relation transform (f32 chain + bf16 copy for gathers)
        k_gemm_rel<<<dim3(4, 4), 256, 0, stream>>>(rc, Wr, rn, relbf, RR, K);
        const float* nr = rn;
        rn = (l == 0) ? relB : (float*)rc;
        rc = nr;
    }

    k_feats<<<GG, 256, 0, stream>>>(xbfA, rc, rel_labels, feats);
    k_head<<<GG, 256, 0, stream>>>(feats, (const float*)d_in[18],
                                   (const float*)d_in[19], out);
}

// Round 12
// 773.644 us; speedup vs baseline: 1.1657x; 1.0527x over previous
//
#include <hip/hip_runtime.h>

#define NN 32768      // total nodes
#define GG 256        // graphs
#define NPGN 128      // nodes per graph
#define ET 524288     // total directed edges
#define EH 262144     // edges per direction
#define D1 128        // input feature dim
#define D2 256        // hidden dim
#define RR 200        // relations

typedef unsigned short u16;
typedef __attribute__((ext_vector_type(8))) short bf16x8;   // MFMA A/B frag (4 VGPR)
typedef __attribute__((ext_vector_type(4))) float f32x4;    // MFMA C/D frag
typedef __attribute__((ext_vector_type(8))) unsigned short u16x8;

__device__ __forceinline__ float bf2f(u16 u) {
    union { unsigned int i; float f; } v; v.i = ((unsigned int)u) << 16; return v.f;
}
__device__ __forceinline__ u16 f2bf(float f) {
    union { unsigned int i; float f; } v; v.f = f;
    unsigned int x = v.i;
    return (u16)((x + 0x7fffu + ((x >> 16) & 1u)) >> 16);   // RNE
}

// ---- histograms: by-src (for norm) and by-dst (for CSR) per direction ----
__global__ void k_hist(const int* __restrict__ ei, int* __restrict__ hs_in,
                       int* __restrict__ hs_out, int* __restrict__ hd_in,
                       int* __restrict__ hd_out) {
    int e = blockIdx.x * blockDim.x + threadIdx.x;
    if (e >= ET) return;
    int s = ei[e], d = ei[ET + e];
    if (e < EH) { atomicAdd(&hs_in[s], 1);  atomicAdd(&hd_in[d], 1); }
    else        { atomicAdd(&hs_out[s], 1); atomicAdd(&hd_out[d], 1); }
}

__global__ void k_dinv(const int* __restrict__ hs_in, const int* __restrict__ hs_out,
                       float* __restrict__ dinv_in, float* __restrict__ dinv_out) {
    int n = blockIdx.x * blockDim.x + threadIdx.x;
    if (n >= NN) return;
    int a = hs_in[n], b = hs_out[n];
    dinv_in[n]  = a > 0 ? rsqrtf((float)a) : 0.f;
    dinv_out[n] = b > 0 ? rsqrtf((float)b) : 0.f;
}

// ---- two independent exclusive scans of 32768 ints (blockIdx.x picks dir) ----
__global__ __launch_bounds__(1024) void k_scan2(const int* __restrict__ hdI,
                                                const int* __restrict__ hdO,
                                                int* __restrict__ offI,
                                                int* __restrict__ offO) {
    const int* __restrict__ hist = blockIdx.x ? hdO : hdI;
    int* __restrict__ off = blockIdx.x ? offO : offI;
    __shared__ int lds[1024];
    int t = threadIdx.x;
    int base = t * 32;
    int loc[32];
    int s = 0;
#pragma unroll
    for (int i = 0; i < 32; ++i) { loc[i] = s; s += hist[base + i]; }
    lds[t] = s;
    int tot = s;
    __syncthreads();
    for (int st = 1; st < 1024; st <<= 1) {
        int v = (t >= st) ? lds[t - st] : 0;
        __syncthreads();
        lds[t] += v;
        __syncthreads();
    }
    int excl = lds[t] - tot;
#pragma unroll
    for (int i = 0; i < 32; ++i) off[base + i] = excl + loc[i];
    if (t == 1023) off[NN] = lds[1023];
}

// ---- fill CSR slots, both directions (blockIdx.y picks dir); norm folded in ----
__global__ void k_fill2(const int* __restrict__ ei, const int* __restrict__ et,
                        const float* __restrict__ dinvI, const float* __restrict__ dinvO,
                        const int* __restrict__ offI, const int* __restrict__ offO,
                        int* __restrict__ curI, int* __restrict__ curO,
                        int* __restrict__ csI, int* __restrict__ csO,
                        int* __restrict__ cetI, int* __restrict__ cetO,
                        float* __restrict__ cnI, float* __restrict__ cnO) {
    int e = blockIdx.x * blockDim.x + threadIdx.x;
    if (e >= EH) return;
    const int dir = blockIdx.y;
    const float* __restrict__ dinv = dir ? dinvO : dinvI;
    const int* __restrict__ off = dir ? offO : offI;
    int* __restrict__ cur = dir ? curO : curI;
    int* __restrict__ c_src = dir ? csO : csI;
    int* __restrict__ c_et = dir ? cetO : cetI;
    float* __restrict__ c_norm = dir ? cnO : cnI;
    const int eoff = dir ? EH : 0;
    int s = ei[eoff + e], d = ei[ET + eoff + e], t = et[eoff + e];
    int slot = off[d] + atomicAdd(&cur[d], 1);
    c_src[slot] = s;
    c_et[slot] = t;
    c_norm[slot] = dinv[s] * dinv[d];
}

// ---- f32 -> bf16, two tensors in one launch ----
__global__ void k_conv2(const float* __restrict__ a, u16* __restrict__ oa, int na,
                        const float* __restrict__ b, u16* __restrict__ ob, int nb) {
    int i = blockIdx.x * blockDim.x + threadIdx.x;
    if (i < na) oa[i] = f2bf(a[i]);
    else if (i < na + nb) ob[i - na] = f2bf(b[i - na]);
}

// ---- weight prep via LDS 32x32 tile transpose (both sides coalesced) ----
__global__ __launch_bounds__(256) void k_prepw(
    const float* __restrict__ Wi, const float* __restrict__ Wo,
    const float* __restrict__ Wl, const float* __restrict__ lr,
    u16* __restrict__ WiT, u16* __restrict__ WoT, u16* __restrict__ WlT, int K) {
    __shared__ float tile[32][33];
    const int fam = blockIdx.z;
    const int l = blockIdx.y;
    const int ntiles_n = 256 / 32;
    const int k0 = (blockIdx.x / ntiles_n) * 32;
    const int n0 = (blockIdx.x % ntiles_n) * 32;
    const float* src = fam == 0 ? Wi : fam == 1 ? Wo : Wl;
    u16* dst = fam == 0 ? WiT : fam == 1 ? WoT : WlT;
    const int tn = threadIdx.x & 31, tk = threadIdx.x >> 5;   // load: n fast
#pragma unroll
    for (int j = 0; j < 4; ++j) {
        int k = k0 + tk + j * 8;
        tile[tk + j * 8][tn] = src[((size_t)l * K + k) * 256 + n0 + tn];
    }
    __syncthreads();
    const int tk2 = threadIdx.x & 31, tn2 = threadIdx.x >> 5; // store: k fast
    float scale = 1.0f;
    if (fam == 2) scale = lr[(size_t)l * K + k0 + tk2];
#pragma unroll
    for (int j = 0; j < 4; ++j) {
        int n = n0 + tn2 + j * 8;
        dst[((size_t)l * 256 + n) * K + k0 + tk2] = f2bf(tile[tk2][tn2 + j * 8] * scale);
    }
}

// ---- gather, both directions: K/8 lanes per node (16B frags), 4-edge unroll ----
// R8's measured-best form. Also zeroes bnsums (block 0) for the GEMM's BN stats.
template <int K>
__global__ __launch_bounds__(256) void k_gather2(
    const u16* __restrict__ x, const u16* __restrict__ relb,
    const int* __restrict__ csI, const int* __restrict__ cetI,
    const float* __restrict__ cnI, const int* __restrict__ offI,
    const int* __restrict__ csO, const int* __restrict__ cetO,
    const float* __restrict__ cnO, const int* __restrict__ offO,
    u16* __restrict__ aggI, u16* __restrict__ aggO, float* __restrict__ bnsums) {
    if (blockIdx.x == 0 && blockIdx.y == 0 && threadIdx.x < 128)
        ((float4*)bnsums)[threadIdx.x] = make_float4(0.f, 0.f, 0.f, 0.f);
    constexpr int LPN = K / 8;            // lanes per node
    constexpr int NPB = 256 / LPN;        // nodes per block
    const int dir = blockIdx.y;
    const int* __restrict__ cs  = dir ? csO : csI;
    const int* __restrict__ cet = dir ? cetO : cetI;
    const float* __restrict__ cn = dir ? cnO : cnI;
    const int* __restrict__ off = dir ? offO : offI;
    u16* __restrict__ agg = dir ? aggO : aggI;

    int node = blockIdx.x * NPB + (threadIdx.x / LPN);
    int lane = threadIdx.x % LPN;
    int c = lane * 8;
    int e0 = off[node], e1 = off[node + 1];
    float acc[8] = {};
    int e = e0;
    for (; e + 4 <= e1; e += 4) {
        int s0 = cs[e],  s1 = cs[e + 1],  s2 = cs[e + 2],  s3 = cs[e + 3];
        int t0 = cet[e], t1 = cet[e + 1], t2 = cet[e + 2], t3 = cet[e + 3];
        float n0 = cn[e], n1 = cn[e + 1], n2 = cn[e + 2], n3 = cn[e + 3];
        u16x8 xa = *(const u16x8*)(x + (size_t)s0 * K + c);
        u16x8 xb = *(const u16x8*)(x + (size_t)s1 * K + c);
        u16x8 xc = *(const u16x8*)(x + (size_t)s2 * K + c);
        u16x8 xd = *(const u16x8*)(x + (size_t)s3 * K + c);
        u16x8 ra = *(const u16x8*)(relb + (size_t)t0 * K + c);
        u16x8 rb = *(const u16x8*)(relb + (size_t)t1 * K + c);
        u16x8 rc = *(const u16x8*)(relb + (size_t)t2 * K + c);
        u16x8 rd = *(const u16x8*)(relb + (size_t)t3 * K + c);
#pragma unroll
        for (int i = 0; i < 8; ++i)
            acc[i] += n0 * bf2f(xa[i]) * bf2f(ra[i]) + n1 * bf2f(xb[i]) * bf2f(rb[i])
                    + n2 * bf2f(xc[i]) * bf2f(rc[i]) + n3 * bf2f(xd[i]) * bf2f(rd[i]);
    }
    for (; e < e1; ++e) {
        int s0 = cs[e], t0 = cet[e]; float n0 = cn[e];
        u16x8 xa = *(const u16x8*)(x + (size_t)s0 * K + c);
        u16x8 ra = *(const u16x8*)(relb + (size_t)t0 * K + c);
#pragma unroll
        for (int i = 0; i < 8; ++i) acc[i] += n0 * bf2f(xa[i]) * bf2f(ra[i]);
    }
    u16x8 o;
#pragma unroll
    for (int i = 0; i < 8; ++i) o[i] = f2bf(acc[i]);
    *(u16x8*)(agg + (size_t)node * K + c) = o;
}

// ---- async stage of one 16-row x 32-k chunk into LDS (global_load_lds x16) ----
__device__ __forceinline__ void stage16(const u16* __restrict__ src, int baseRow,
                                        int K, int kk, u16* lds, int chunk, int lane) {
    int row = chunk * 16 + (lane >> 2);
    int ks  = (lane & 3) ^ ((lane >> 2) & 3);
    const u16* g = src + (size_t)(baseRow + row) * K + kk + ks * 8;
    __builtin_amdgcn_global_load_lds((const __attribute__((address_space(1))) void*)g,
                                     (__attribute__((address_space(3))) void*)(lds + chunk * 512),
                                     16, 0, 0);
}

// ---- fused 3-segment MFMA GEMM, 128x128 tile (R8 config), bf16 h + BN stats ----
template <int K>
__global__ __launch_bounds__(256) void k_gemm_mfma(
    const u16* __restrict__ A1, const u16* __restrict__ A2, const u16* __restrict__ A3,
    const u16* __restrict__ W1, const u16* __restrict__ W2, const u16* __restrict__ W3,
    const float* __restrict__ bias, u16* __restrict__ hb, float* __restrict__ bnsums) {
    __shared__ u16 As_s[2][128 * 32];
    __shared__ u16 Ws_s[2][128 * 32];
    const int tid = threadIdx.x;
    const int wave = tid >> 6, lane = tid & 63;
    const int q = lane >> 4, r = lane & 15;
    const int rowBlk = blockIdx.x * 128;
    const int colBlk = blockIdx.y * 128;
    const int rowBase = rowBlk + (wave & 1) * 64;
    const int colBase = colBlk + (wave >> 1) * 64;

    f32x4 zero = {0.f, 0.f, 0.f, 0.f};
    f32x4 acc[4][4];
#pragma unroll
    for (int i = 0; i < 4; ++i)
#pragma unroll
        for (int j = 0; j < 4; ++j) acc[i][j] = zero;

    const u16* As[3] = {A1, A2, A3};
    const u16* Ws[3] = {W1, W2, W3};
    constexpr int SPS = K / 32;
    constexpr int TOT = 3 * SPS;

    stage16(As[0], rowBlk, K, 0, As_s[0], 2 * wave, lane);
    stage16(As[0], rowBlk, K, 0, As_s[0], 2 * wave + 1, lane);
    stage16(Ws[0], colBlk, K, 0, Ws_s[0], 2 * wave, lane);
    stage16(Ws[0], colBlk, K, 0, Ws_s[0], 2 * wave + 1, lane);

    const int sw = (q ^ (r & 3)) * 8;   // matches the stage-side k-slot permutation
    for (int s = 0; s < TOT; ++s) {
        __syncthreads();
        if (s + 1 < TOT) {
            int seg = (s + 1) / SPS;
            int kk  = ((s + 1) % SPS) * 32;
            stage16(As[seg], rowBlk, K, kk, As_s[(s + 1) & 1], 2 * wave, lane);
            stage16(As[seg], rowBlk, K, kk, As_s[(s + 1) & 1], 2 * wave + 1, lane);
            stage16(Ws[seg], colBlk, K, kk, Ws_s[(s + 1) & 1], 2 * wave, lane);
            stage16(Ws[seg], colBlk, K, kk, Ws_s[(s + 1) & 1], 2 * wave + 1, lane);
        }
        const u16* al = As_s[s & 1] + (wave & 1) * 64 * 32;
        const u16* wl = Ws_s[s & 1] + (wave >> 1) * 64 * 32;
        bf16x8 a[4], b[4];
#pragma unroll
        for (int t = 0; t < 4; ++t) {
            a[t] = *(const bf16x8*)(al + (t * 16 + r) * 32 + sw);
            b[t] = *(const bf16x8*)(wl + (t * 16 + r) * 32 + sw);
        }
#pragma unroll
        for (int tm = 0; tm < 4; ++tm)
#pragma unroll
            for (int tn = 0; tn < 4; ++tn)
                acc[tm][tn] = __builtin_amdgcn_mfma_f32_16x16x32_bf16(
                    a[tm], b[tn], acc[tm][tn], 0, 0, 0);
    }

#pragma unroll
    for (int tn = 0; tn < 4; ++tn) {
        int col = colBase + tn * 16 + r;
        float bv = bias[col];
        float sv = 0.f, qv = 0.f;
#pragma unroll
        for (int tm = 0; tm < 4; ++tm) {
#pragma unroll
            for (int reg = 0; reg < 4; ++reg) {
                int row = rowBase + tm * 16 + q * 4 + reg;
                float v = acc[tm][tn][reg] * (1.0f / 3.0f) + bv;
                hb[(size_t)row * 256 + col] = f2bf(v);
                sv += v; qv += v * v;
            }
        }
        sv += __shfl_xor(sv, 16); sv += __shfl_xor(sv, 32);
        qv += __shfl_xor(qv, 16); qv += __shfl_xor(qv, 32);
        if (q == 0) {
            atomicAdd(&bnsums[col], sv);
            atomicAdd(&bnsums[256 + col], qv);
        }
    }
}

// ---- fused per-layer tail: BN-apply+ReLU (blocks 0..4095) + rel-chain GEMM ----
// bnapply: xb = bf16(relu((h-mean)*inv*gamma+beta)), 8 elems/thread.
// gemm_rel (blocks 4096..4111): C = A @ W (f32) and Cb = bf16(C).
__global__ __launch_bounds__(256) void k_bnrel(
    const u16x8* __restrict__ hb8, const float* __restrict__ sums,
    const float* __restrict__ gamma, const float* __restrict__ beta,
    u16x8* __restrict__ xb8,
    const float* __restrict__ A, const float* __restrict__ W,
    float* __restrict__ C, u16* __restrict__ Cb, int M, int K) {
    __shared__ float As[16][68];
    __shared__ float Wshm[16][68];
    if (blockIdx.x < 4096) {
        int idx = blockIdx.x * 256 + threadIdx.x;
        int f0 = (idx & 31) << 3;
        u16x8 v = hb8[idx];
        u16x8 o;
#pragma unroll
        for (int i = 0; i < 8; ++i) {
            int f = f0 + i;
            float mean = sums[f] * (1.0f / NN);
            float var  = sums[256 + f] * (1.0f / NN) - mean * mean;
            float inv  = 1.0f / sqrtf(var + 1e-5f);
            float t = (bf2f(v[i]) - mean) * inv * gamma[f] + beta[f];
            o[i] = f2bf(t > 0.f ? t : 0.f);
        }
        xb8[idx] = o;
        return;
    }
    const int bx = blockIdx.x - 4096;         // 0..15
    const int rowBase = (bx & 3) << 6;
    const int colBase = (bx >> 2) << 6;
    const int tid = threadIdx.x;
    const int tx = tid & 15, ty = tid >> 4;
    const int arow = tid >> 2;
    const int akc  = (tid & 3) << 2;
    const int wk   = tid >> 4;
    const int wn0  = (tid & 15) << 2;
    float acc[4][4] = {};
    for (int k0 = 0; k0 < K; k0 += 16) {
        float4 av = make_float4(0.f, 0.f, 0.f, 0.f);
        int rr = rowBase + arow;
        if (rr < M) av = *(const float4*)(A + (size_t)rr * K + k0 + akc);
        As[akc + 0][arow] = av.x;
        As[akc + 1][arow] = av.y;
        As[akc + 2][arow] = av.z;
        As[akc + 3][arow] = av.w;
        float4 wv = *(const float4*)(W + (size_t)(k0 + wk) * D2 + colBase + wn0);
        Wshm[wk][wn0 + 0] = wv.x;
        Wshm[wk][wn0 + 1] = wv.y;
        Wshm[wk][wn0 + 2] = wv.z;
        Wshm[wk][wn0 + 3] = wv.w;
        __syncthreads();
#pragma unroll
        for (int kk = 0; kk < 16; ++kk) {
            float a0 = As[kk][(ty << 2) + 0], a1 = As[kk][(ty << 2) + 1];
            float a2 = As[kk][(ty << 2) + 2], a3 = As[kk][(ty << 2) + 3];
            float w0 = Wshm[kk][(tx << 2) + 0], w1 = Wshm[kk][(tx << 2) + 1];
            float w2 = Wshm[kk][(tx << 2) + 2], w3 = Wshm[kk][(tx << 2) + 3];
            acc[0][0] += a0 * w0; acc[0][1] += a0 * w1; acc[0][2] += a0 * w2; acc[0][3] += a0 * w3;
            acc[1][0] += a1 * w0; acc[1][1] += a1 * w1; acc[1][2] += a1 * w2; acc[1][3] += a1 * w3;
            acc[2][0] += a2 * w0; acc[2][1] += a2 * w1; acc[2][2] += a2 * w2; acc[2][3] += a2 * w3;
            acc[3][0] += a3 * w0; acc[3][1] += a3 * w1; acc[3][2] += a3 * w2; acc[3][3] += a3 * w3;
        }
        __syncthreads();
    }
#pragma unroll
    for (int i = 0; i < 4; ++i) {
        int rr = rowBase + (ty << 2) + i;
        if (rr >= M) continue;
        float* cp = C + (size_t)rr * D2 + colBase + (tx << 2);
        u16* cb = Cb + (size_t)rr * D2 + colBase + (tx << 2);
        cp[0] = acc[i][0]; cp[1] = acc[i][1]; cp[2] = acc[i][2]; cp[3] = acc[i][3];
        cb[0] = f2bf(acc[i][0]); cb[1] = f2bf(acc[i][1]);
        cb[2] = f2bf(acc[i][2]); cb[3] = f2bf(acc[i][3]);
    }
}

// ---- head features ----
__global__ void k_feats(const u16* __restrict__ x, const float* __restrict__ rel,
                        const int* __restrict__ rel_labels, float* __restrict__ feats) {
    int g = blockIdx.x, f = threadIdx.x;
    const u16* xg = x + (size_t)g * NPGN * D2;
    float s = 0.f;
#pragma unroll 8
    for (int n = 0; n < NPGN; ++n) s += bf2f(xg[(size_t)n * D2 + f]);
    float* fg = feats + (size_t)g * 1024;
    fg[f]       = s * (1.0f / NPGN);
    fg[256 + f] = rel[(size_t)rel_labels[g] * D2 + f];
    fg[512 + f] = bf2f(xg[f]);
    fg[768 + f] = bf2f(xg[D2 + f]);
}

// ---- final linear ----
__global__ void k_head(const float* __restrict__ feats, const float* __restrict__ lw,
                       const float* __restrict__ lb, float* __restrict__ out) {
    int g = blockIdx.x, t = threadIdx.x;
    __shared__ float s0[256], s1[256];
    float a0 = 0.f, a1 = 0.f;
#pragma unroll
    for (int j = 0; j < 4; ++j) {
        int k = t * 4 + j;
        float fv = feats[(size_t)g * 1024 + k];
        a0 += fv * lw[k * 2 + 0];
        a1 += fv * lw[k * 2 + 1];
    }
    s0[t] = a0; s1[t] = a1;
    __syncthreads();
    for (int s = 128; s > 0; s >>= 1) {
        if (t < s) { s0[t] += s0[t + s]; s1[t] += s1[t + s]; }
        __syncthreads();
    }
    if (t == 0) {
        out[g * 2 + 0] = s0[0] + lb[0];
        out[g * 2 + 1] = s1[0] + lb[1];
    }
}

extern "C" void kernel_launch(void* const* d_in, const int* in_sizes, int n_in,
                              void* d_out, int out_size, void* d_ws, size_t ws_size,
                              hipStream_t stream) {
    const float* x0   = (const float*)d_in[0];
    const float* rel0 = (const float*)d_in[1];
    const int* edge_index = (const int*)d_in[20];
    const int* edge_type  = (const int*)d_in[21];
    const int* rel_labels = (const int*)d_in[23];
    float* out = (float*)d_out;

    // ---- workspace carve (~70 MB) ----
    float* ws = (float*)d_ws;
    float* relA  = ws;                              // RR*256
    float* relB  = relA + (size_t)RR * 256;         // RR*256
    float* dinv_in  = relB + (size_t)RR * 256;      // NN
    float* dinv_out = dinv_in + NN;                 // NN
    float* cnorm_in  = dinv_out + NN;               // EH
    float* cnorm_out = cnorm_in + EH;               // EH
    float* bnsums    = cnorm_out + EH;              // 512
    float* feats     = bnsums + 512;                // GG*1024
    int* csrc_in  = (int*)(feats + GG * 1024);      // EH
    int* cet_in   = csrc_in + EH;                   // EH
    int* csrc_out = cet_in + EH;                    // EH
    int* cet_out  = csrc_out + EH;                  // EH
    int* off_in   = cet_out + EH;                   // NN+8
    int* off_out  = off_in + NN + 8;                // NN+8
    int* hs_in    = off_out + NN + 8;               // NN  -- zeroed region start
    int* hs_out   = hs_in + NN;                     // NN
    int* hd_in    = hs_out + NN;                    // NN
    int* hd_out   = hd_in + NN;                     // NN
    int* cur_in   = hd_out + NN;                    // NN
    int* cur_out  = cur_in + NN;                    // NN -- zeroed region end
    u16* xbf0 = (u16*)(cur_out + NN);               // NN*128 bf16
    u16* xbfA = xbf0 + (size_t)NN * 128;            // NN*256 bf16
    u16* aggI = xbfA + (size_t)NN * 256;            // NN*256 bf16
    u16* aggO = aggI + (size_t)NN * 256;            // NN*256 bf16
    u16* hb   = aggO + (size_t)NN * 256;            // NN*256 bf16 (pre-BN h)
    u16* wt0  = hb + (size_t)NN * 256;              // 3*256*128
    u16* wtS  = wt0 + 3 * 256 * 128;                // 12*256*256
    u16* relbf = wtS + 12 * 65536;                  // RR*256 bf16

    // ---- CSR build + conversions + weight prep (once per launch) ----
    hipMemsetAsync(hs_in, 0, 6 * NN * sizeof(int), stream);
    k_hist<<<ET / 256, 256, 0, stream>>>(edge_index, hs_in, hs_out, hd_in, hd_out);
    k_dinv<<<NN / 256, 256, 0, stream>>>(hs_in, hs_out, dinv_in, dinv_out);
    k_scan2<<<2, 1024, 0, stream>>>(hd_in, hd_out, off_in, off_out);
    k_fill2<<<dim3(EH / 256, 2), 256, 0, stream>>>(edge_index, edge_type,
        dinv_in, dinv_out, off_in, off_out, cur_in, cur_out,
        csrc_in, csrc_out, cet_in, cet_out, cnorm_in, cnorm_out);
    k_conv2<<<(NN * D1 + RR * D1 + 255) / 256, 256, 0, stream>>>(
        x0, xbf0, NN * D1, rel0, relbf, RR * D1);
    {
        dim3 g0((D1 / 32) * 8, 1, 3);   // layer-0 weights: K=128
        k_prepw<<<g0, 256, 0, stream>>>(
            (const float*)d_in[2], (const float*)d_in[3], (const float*)d_in[4],
            (const float*)d_in[6], wt0, wt0 + 256 * D1, wt0 + 2 * 256 * D1, D1);
        dim3 gS((D2 / 32) * 8, 4, 3);   // stacked weights: K=256, L=4
        k_prepw<<<gS, 256, 0, stream>>>(
            (const float*)d_in[10], (const float*)d_in[11], (const float*)d_in[12],
            (const float*)d_in[14], wtS, wtS + 4 * 65536, wtS + 8 * 65536, D2);
    }

    const float* rc = rel0; float* rn = relA;

    for (int l = 0; l < 5; ++l) {
        const int K = (l == 0) ? D1 : D2;
        const u16* xb = (l == 0) ? xbf0 : xbfA;
        const u16 *WiT, *WoT, *WlT;
        const float *Wr, *bias, *gamma, *beta;
        if (l == 0) {
            WiT = wt0; WoT = wt0 + 256 * D1; WlT = wt0 + 2 * 256 * D1;
            Wr = (const float*)d_in[5];
            bias  = (const float*)d_in[7];
            gamma = (const float*)d_in[8];
            beta  = (const float*)d_in[9];
        } else {
            int m = l - 1;
            WiT = wtS + (size_t)m * 65536;
            WoT = wtS + (size_t)(4 + m) * 65536;
            WlT = wtS + (size_t)(8 + m) * 65536;
            Wr = (const float*)d_in[13] + (size_t)m * D2 * D2;
            bias  = (const float*)d_in[15] + (size_t)m * D2;
            gamma = (const float*)d_in[16] + (size_t)m * D2;
            beta  = (const float*)d_in[17] + (size_t)m * D2;
        }

        // both-direction gather into bf16 agg buffers (zeroes bnsums too)
        if (K == D1) {
            dim3 ggr(NN / 16, 2);
            k_gather2<D1><<<ggr, 256, 0, stream>>>(xb, relbf, csrc_in, cet_in,
                cnorm_in, off_in, csrc_out, cet_out, cnorm_out, off_out, aggI, aggO, bnsums);
        } else {
            dim3 ggr(NN / 8, 2);
            k_gather2<D2><<<ggr, 256, 0, stream>>>(xb, relbf, csrc_in, cet_in,
                cnorm_in, off_in, csrc_out, cet_out, cnorm_out, off_out, aggI, aggO, bnsums);
        }
        // fused 3-segment MFMA GEMM (128x128 tiles) + BN stats, bf16 h out
        dim3 ggrid(NN / 128, 2);
        if (K == D1) k_gemm_mfma<D1><<<ggrid, 256, 0, stream>>>(aggI, aggO, xb, WiT, WoT, WlT, bias, hb, bnsums);
        else         k_gemm_mfma<D2><<<ggrid, 256, 0, stream>>>(aggI, aggO, xb, WiT, WoT, WlT, bias, hb, bnsums);
        // fused tail: BN apply + relu -> bf16 x, and rel chain GEMM (+bf16 copy)
        k_bnrel<<<4096 + 16, 256, 0, stream>>>((const u16x8*)hb, bnsums, gamma, beta,
                                               (u16x8*)xbfA, rc, Wr, rn, relbf, RR, K);
        const float* nr = rn;
        rn = (l == 0) ? relB : (float*)rc;
        rc = nr;
    }

    k_feats<<<GG, 256, 0, stream>>>(xbfA, rc, rel_labels, feats);
    k_head<<<GG, 256, 0, stream>>>(feats, (const float*)d_in[18],
                                   (const float*)d_in[19], out);
}

// Round 13
// 756.401 us; speedup vs baseline: 1.1923x; 1.0228x over previous
//
#include <hip/hip_runtime.h>

#define NN 32768      // total nodes
#define GG 256        // graphs
#define NPGN 128      // nodes per graph
#define ET 524288     // total directed edges
#define EH 262144     // edges per direction
#define D1 128        // input feature dim
#define D2 256        // hidden dim
#define RR 200        // relations

typedef unsigned short u16;
typedef __attribute__((ext_vector_type(8))) short bf16x8;   // MFMA A/B frag (4 VGPR)
typedef __attribute__((ext_vector_type(4))) float f32x4;    // MFMA C/D frag
typedef __attribute__((ext_vector_type(8))) unsigned short u16x8;

__device__ __forceinline__ float bf2f(u16 u) {
    union { unsigned int i; float f; } v; v.i = ((unsigned int)u) << 16; return v.f;
}
__device__ __forceinline__ u16 f2bf(float f) {
    union { unsigned int i; float f; } v; v.f = f;
    unsigned int x = v.i;
    return (u16)((x + 0x7fffu + ((x >> 16) & 1u)) >> 16);   // RNE
}

// ---- histograms: by-src (for norm) and by-dst (for CSR) per direction ----
__global__ void k_hist(const int* __restrict__ ei, int* __restrict__ hs_in,
                       int* __restrict__ hs_out, int* __restrict__ hd_in,
                       int* __restrict__ hd_out) {
    int e = blockIdx.x * blockDim.x + threadIdx.x;
    if (e >= ET) return;
    int s = ei[e], d = ei[ET + e];
    if (e < EH) { atomicAdd(&hs_in[s], 1);  atomicAdd(&hd_in[d], 1); }
    else        { atomicAdd(&hs_out[s], 1); atomicAdd(&hd_out[d], 1); }
}

// ---- fused: dinv (blocks 0..31) + two exclusive scans (blocks 32,33) ----
__global__ __launch_bounds__(1024) void k_build(
    const int* __restrict__ hs_in, const int* __restrict__ hs_out,
    float* __restrict__ dinv_in, float* __restrict__ dinv_out,
    const int* __restrict__ hdI, const int* __restrict__ hdO,
    int* __restrict__ offI, int* __restrict__ offO) {
    if (blockIdx.x < 32) {
        int n = blockIdx.x * 1024 + threadIdx.x;
        int a = hs_in[n], b = hs_out[n];
        dinv_in[n]  = a > 0 ? rsqrtf((float)a) : 0.f;
        dinv_out[n] = b > 0 ? rsqrtf((float)b) : 0.f;
        return;
    }
    const int* __restrict__ hist = (blockIdx.x == 33) ? hdO : hdI;
    int* __restrict__ off = (blockIdx.x == 33) ? offO : offI;
    __shared__ int lds[1024];
    int t = threadIdx.x;
    int base = t * 32;
    int loc[32];
    int s = 0;
#pragma unroll
    for (int i = 0; i < 32; ++i) { loc[i] = s; s += hist[base + i]; }
    lds[t] = s;
    int tot = s;
    __syncthreads();
    for (int st = 1; st < 1024; st <<= 1) {
        int v = (t >= st) ? lds[t - st] : 0;
        __syncthreads();
        lds[t] += v;
        __syncthreads();
    }
    int excl = lds[t] - tot;
#pragma unroll
    for (int i = 0; i < 32; ++i) off[base + i] = excl + loc[i];
    if (t == 1023) off[NN] = lds[1023];
}

// ---- fill CSR slots, both directions (blockIdx.y picks dir); norm folded in ----
__global__ void k_fill2(const int* __restrict__ ei, const int* __restrict__ et,
                        const float* __restrict__ dinvI, const float* __restrict__ dinvO,
                        const int* __restrict__ offI, const int* __restrict__ offO,
                        int* __restrict__ curI, int* __restrict__ curO,
                        int* __restrict__ csI, int* __restrict__ csO,
                        int* __restrict__ cetI, int* __restrict__ cetO,
                        float* __restrict__ cnI, float* __restrict__ cnO) {
    int e = blockIdx.x * blockDim.x + threadIdx.x;
    if (e >= EH) return;
    const int dir = blockIdx.y;
    const float* __restrict__ dinv = dir ? dinvO : dinvI;
    const int* __restrict__ off = dir ? offO : offI;
    int* __restrict__ cur = dir ? curO : curI;
    int* __restrict__ c_src = dir ? csO : csI;
    int* __restrict__ c_et = dir ? cetO : cetI;
    float* __restrict__ c_norm = dir ? cnO : cnI;
    const int eoff = dir ? EH : 0;
    int s = ei[eoff + e], d = ei[ET + eoff + e], t = et[eoff + e];
    int slot = off[d] + atomicAdd(&cur[d], 1);
    c_src[slot] = s;
    c_et[slot] = t;
    c_norm[slot] = dinv[s] * dinv[d];
}

// ---- weight-prep tile transpose body (LDS 32x32; both sides coalesced) ----
__device__ __forceinline__ void prepw_tile(const float* __restrict__ src,
                                           const float* __restrict__ lr, bool scaleit,
                                           u16* __restrict__ dst, int K, int l, int bx) {
    __shared__ float tile[32][33];
    const int ntiles_n = 256 / 32;
    const int k0 = (bx / ntiles_n) * 32;
    const int n0 = (bx % ntiles_n) * 32;
    const int tn = threadIdx.x & 31, tk = threadIdx.x >> 5;   // load: n fast
#pragma unroll
    for (int j = 0; j < 4; ++j) {
        int k = k0 + tk + j * 8;
        tile[tk + j * 8][tn] = src[((size_t)l * K + k) * 256 + n0 + tn];
    }
    __syncthreads();
    const int tk2 = threadIdx.x & 31, tn2 = threadIdx.x >> 5; // store: k fast
    float scale = 1.0f;
    if (scaleit) scale = lr[(size_t)l * K + k0 + tk2];
#pragma unroll
    for (int j = 0; j < 4; ++j) {
        int n = n0 + tn2 + j * 8;
        dst[((size_t)l * 256 + n) * K + k0 + tk2] = f2bf(tile[tk2][tn2 + j * 8] * scale);
    }
}

// ---- fused prep: conv-x | conv-rel | prepw layer0 | prepw stacked ----
// blocks [0,2048): x f32->bf16 (8/thread); [2048,2061): rel f32->bf16;
// [2061,2157): prepw0 (fam*32+bx); [2157,2925): prepwS (fam*256 + l*64 + bx)
__global__ __launch_bounds__(256) void k_prep(
    const float* __restrict__ x0, u16* __restrict__ xbf0,
    const float* __restrict__ rel0, u16* __restrict__ relbf,
    const float* __restrict__ Wi0, const float* __restrict__ Wo0,
    const float* __restrict__ Wl0, const float* __restrict__ lr0,
    u16* __restrict__ WiT0, u16* __restrict__ WoT0, u16* __restrict__ WlT0,
    const float* __restrict__ WiS, const float* __restrict__ WoS,
    const float* __restrict__ WlS, const float* __restrict__ lrS,
    u16* __restrict__ WiTS, u16* __restrict__ WoTS, u16* __restrict__ WlTS) {
    const int b = blockIdx.x;
    if (b < 2048) {
        int i8 = b * 256 + threadIdx.x;        // item = 8 consecutive elems
        const float4* in = (const float4*)(x0) + i8 * 2;
        float4 a = in[0], c = in[1];
        u16x8 o;
        o[0] = f2bf(a.x); o[1] = f2bf(a.y); o[2] = f2bf(a.z); o[3] = f2bf(a.w);
        o[4] = f2bf(c.x); o[5] = f2bf(c.y); o[6] = f2bf(c.z); o[7] = f2bf(c.w);
        ((u16x8*)xbf0)[i8] = o;
        return;
    }
    if (b < 2061) {
        int i8 = (b - 2048) * 256 + threadIdx.x;
        if (i8 >= RR * D1 / 8) return;
        const float4* in = (const float4*)(rel0) + i8 * 2;
        float4 a = in[0], c = in[1];
        u16x8 o;
        o[0] = f2bf(a.x); o[1] = f2bf(a.y); o[2] = f2bf(a.z); o[3] = f2bf(a.w);
        o[4] = f2bf(c.x); o[5] = f2bf(c.y); o[6] = f2bf(c.z); o[7] = f2bf(c.w);
        ((u16x8*)relbf)[i8] = o;
        return;
    }
    if (b < 2157) {
        int idx = b - 2061;                    // fam*32 + bx  (K=128: 4*8=32 tiles)
        int fam = idx / 32, bx = idx % 32;
        const float* src = fam == 0 ? Wi0 : fam == 1 ? Wo0 : Wl0;
        u16* dst = fam == 0 ? WiT0 : fam == 1 ? WoT0 : WlT0;
        prepw_tile(src, lr0, fam == 2, dst, D1, 0, bx);
        return;
    }
    int idx = b - 2157;                        // fam*256 + l*64 + bx (K=256: 8*8=64)
    int fam = idx / 256, rem = idx % 256;
    int l = rem / 64, bx = rem % 64;
    const float* src = fam == 0 ? WiS : fam == 1 ? WoS : WlS;
    u16* dst = fam == 0 ? WiTS : fam == 1 ? WoTS : WlTS;
    prepw_tile(src, lrS, fam == 2, dst, D2, l, bx);
}

// ---- gather, both directions: K/8 lanes per node (16B frags), 4-edge unroll ----
// R8's measured-best form. Also zeroes bnsums (block 0) for the GEMM's BN stats.
template <int K>
__global__ __launch_bounds__(256) void k_gather2(
    const u16* __restrict__ x, const u16* __restrict__ relb,
    const int* __restrict__ csI, const int* __restrict__ cetI,
    const float* __restrict__ cnI, const int* __restrict__ offI,
    const int* __restrict__ csO, const int* __restrict__ cetO,
    const float* __restrict__ cnO, const int* __restrict__ offO,
    u16* __restrict__ aggI, u16* __restrict__ aggO, float* __restrict__ bnsums) {
    if (blockIdx.x == 0 && blockIdx.y == 0 && threadIdx.x < 128)
        ((float4*)bnsums)[threadIdx.x] = make_float4(0.f, 0.f, 0.f, 0.f);
    constexpr int LPN = K / 8;            // lanes per node
    constexpr int NPB = 256 / LPN;        // nodes per block
    const int dir = blockIdx.y;
    const int* __restrict__ cs  = dir ? csO : csI;
    const int* __restrict__ cet = dir ? cetO : cetI;
    const float* __restrict__ cn = dir ? cnO : cnI;
    const int* __restrict__ off = dir ? offO : offI;
    u16* __restrict__ agg = dir ? aggO : aggI;

    int node = blockIdx.x * NPB + (threadIdx.x / LPN);
    int lane = threadIdx.x % LPN;
    int c = lane * 8;
    int e0 = off[node], e1 = off[node + 1];
    float acc[8] = {};
    int e = e0;
    for (; e + 4 <= e1; e += 4) {
        int s0 = cs[e],  s1 = cs[e + 1],  s2 = cs[e + 2],  s3 = cs[e + 3];
        int t0 = cet[e], t1 = cet[e + 1], t2 = cet[e + 2], t3 = cet[e + 3];
        float n0 = cn[e], n1 = cn[e + 1], n2 = cn[e + 2], n3 = cn[e + 3];
        u16x8 xa = *(const u16x8*)(x + (size_t)s0 * K + c);
        u16x8 xb = *(const u16x8*)(x + (size_t)s1 * K + c);
        u16x8 xc = *(const u16x8*)(x + (size_t)s2 * K + c);
        u16x8 xd = *(const u16x8*)(x + (size_t)s3 * K + c);
        u16x8 ra = *(const u16x8*)(relb + (size_t)t0 * K + c);
        u16x8 rb = *(const u16x8*)(relb + (size_t)t1 * K + c);
        u16x8 rc = *(const u16x8*)(relb + (size_t)t2 * K + c);
        u16x8 rd = *(const u16x8*)(relb + (size_t)t3 * K + c);
#pragma unroll
        for (int i = 0; i < 8; ++i)
            acc[i] += n0 * bf2f(xa[i]) * bf2f(ra[i]) + n1 * bf2f(xb[i]) * bf2f(rb[i])
                    + n2 * bf2f(xc[i]) * bf2f(rc[i]) + n3 * bf2f(xd[i]) * bf2f(rd[i]);
    }
    for (; e < e1; ++e) {
        int s0 = cs[e], t0 = cet[e]; float n0 = cn[e];
        u16x8 xa = *(const u16x8*)(x + (size_t)s0 * K + c);
        u16x8 ra = *(const u16x8*)(relb + (size_t)t0 * K + c);
#pragma unroll
        for (int i = 0; i < 8; ++i) acc[i] += n0 * bf2f(xa[i]) * bf2f(ra[i]);
    }
    u16x8 o;
#pragma unroll
    for (int i = 0; i < 8; ++i) o[i] = f2bf(acc[i]);
    *(u16x8*)(agg + (size_t)node * K + c) = o;
}

// ---- async stage of one 16-row x 32-k chunk into LDS (global_load_lds x16) ----
__device__ __forceinline__ void stage16(const u16* __restrict__ src, int baseRow,
                                        int K, int kk, u16* lds, int chunk, int lane) {
    int row = chunk * 16 + (lane >> 2);
    int ks  = (lane & 3) ^ ((lane >> 2) & 3);
    const u16* g = src + (size_t)(baseRow + row) * K + kk + ks * 8;
    __builtin_amdgcn_global_load_lds((const __attribute__((address_space(1))) void*)g,
                                     (__attribute__((address_space(3))) void*)(lds + chunk * 512),
                                     16, 0, 0);
}

// ---- fused 3-segment MFMA GEMM, 128x128 tile (R8 config), bf16 h + BN stats ----
template <int K>
__global__ __launch_bounds__(256) void k_gemm_mfma(
    const u16* __restrict__ A1, const u16* __restrict__ A2, const u16* __restrict__ A3,
    const u16* __restrict__ W1, const u16* __restrict__ W2, const u16* __restrict__ W3,
    const float* __restrict__ bias, u16* __restrict__ hb, float* __restrict__ bnsums) {
    __shared__ u16 As_s[2][128 * 32];
    __shared__ u16 Ws_s[2][128 * 32];
    const int tid = threadIdx.x;
    const int wave = tid >> 6, lane = tid & 63;
    const int q = lane >> 4, r = lane & 15;
    const int rowBlk = blockIdx.x * 128;
    const int colBlk = blockIdx.y * 128;
    const int rowBase = rowBlk + (wave & 1) * 64;
    const int colBase = colBlk + (wave >> 1) * 64;

    f32x4 zero = {0.f, 0.f, 0.f, 0.f};
    f32x4 acc[4][4];
#pragma unroll
    for (int i = 0; i < 4; ++i)
#pragma unroll
        for (int j = 0; j < 4; ++j) acc[i][j] = zero;

    const u16* As[3] = {A1, A2, A3};
    const u16* Ws[3] = {W1, W2, W3};
    constexpr int SPS = K / 32;
    constexpr int TOT = 3 * SPS;

    stage16(As[0], rowBlk, K, 0, As_s[0], 2 * wave, lane);
    stage16(As[0], rowBlk, K, 0, As_s[0], 2 * wave + 1, lane);
    stage16(Ws[0], colBlk, K, 0, Ws_s[0], 2 * wave, lane);
    stage16(Ws[0], colBlk, K, 0, Ws_s[0], 2 * wave + 1, lane);

    const int sw = (q ^ (r & 3)) * 8;   // matches the stage-side k-slot permutation
    for (int s = 0; s < TOT; ++s) {
        __syncthreads();
        if (s + 1 < TOT) {
            int seg = (s + 1) / SPS;
            int kk  = ((s + 1) % SPS) * 32;
            stage16(As[seg], rowBlk, K, kk, As_s[(s + 1) & 1], 2 * wave, lane);
            stage16(As[seg], rowBlk, K, kk, As_s[(s + 1) & 1], 2 * wave + 1, lane);
            stage16(Ws[seg], colBlk, K, kk, Ws_s[(s + 1) & 1], 2 * wave, lane);
            stage16(Ws[seg], colBlk, K, kk, Ws_s[(s + 1) & 1], 2 * wave + 1, lane);
        }
        const u16* al = As_s[s & 1] + (wave & 1) * 64 * 32;
        const u16* wl = Ws_s[s & 1] + (wave >> 1) * 64 * 32;
        bf16x8 a[4], b[4];
#pragma unroll
        for (int t = 0; t < 4; ++t) {
            a[t] = *(const bf16x8*)(al + (t * 16 + r) * 32 + sw);
            b[t] = *(const bf16x8*)(wl + (t * 16 + r) * 32 + sw);
        }
#pragma unroll
        for (int tm = 0; tm < 4; ++tm)
#pragma unroll
            for (int tn = 0; tn < 4; ++tn)
                acc[tm][tn] = __builtin_amdgcn_mfma_f32_16x16x32_bf16(
                    a[tm], b[tn], acc[tm][tn], 0, 0, 0);
    }

#pragma unroll
    for (int tn = 0; tn < 4; ++tn) {
        int col = colBase + tn * 16 + r;
        float bv = bias[col];
        float sv = 0.f, qv = 0.f;
#pragma unroll
        for (int tm = 0; tm < 4; ++tm) {
#pragma unroll
            for (int reg = 0; reg < 4; ++reg) {
                int row = rowBase + tm * 16 + q * 4 + reg;
                float v = acc[tm][tn][reg] * (1.0f / 3.0f) + bv;
                hb[(size_t)row * 256 + col] = f2bf(v);
                sv += v; qv += v * v;
            }
        }
        sv += __shfl_xor(sv, 16); sv += __shfl_xor(sv, 32);
        qv += __shfl_xor(qv, 16); qv += __shfl_xor(qv, 32);
        if (q == 0) {
            atomicAdd(&bnsums[col], sv);
            atomicAdd(&bnsums[256 + col], qv);
        }
    }
}

// ---- fused per-layer tail: BN-apply+ReLU (blocks 0..4095) + rel-chain GEMM ----
__global__ __launch_bounds__(256) void k_bnrel(
    const u16x8* __restrict__ hb8, const float* __restrict__ sums,
    const float* __restrict__ gamma, const float* __restrict__ beta,
    u16x8* __restrict__ xb8,
    const float* __restrict__ A, const float* __restrict__ W,
    float* __restrict__ C, u16* __restrict__ Cb, int M, int K) {
    __shared__ float As[16][68];
    __shared__ float Wshm[16][68];
    if (blockIdx.x < 4096) {
        int idx = blockIdx.x * 256 + threadIdx.x;
        int f0 = (idx & 31) << 3;
        u16x8 v = hb8[idx];
        u16x8 o;
#pragma unroll
        for (int i = 0; i < 8; ++i) {
            int f = f0 + i;
            float mean = sums[f] * (1.0f / NN);
            float var  = sums[256 + f] * (1.0f / NN) - mean * mean;
            float inv  = 1.0f / sqrtf(var + 1e-5f);
            float t = (bf2f(v[i]) - mean) * inv * gamma[f] + beta[f];
            o[i] = f2bf(t > 0.f ? t : 0.f);
        }
        xb8[idx] = o;
        return;
    }
    const int bx = blockIdx.x - 4096;         // 0..15
    const int rowBase = (bx & 3) << 6;
    const int colBase = (bx >> 2) << 6;
    const int tid = threadIdx.x;
    const int tx = tid & 15, ty = tid >> 4;
    const int arow = tid >> 2;
    const int akc  = (tid & 3) << 2;
    const int wk   = tid >> 4;
    const int wn0  = (tid & 15) << 2;
    float acc[4][4] = {};
    for (int k0 = 0; k0 < K; k0 += 16) {
        float4 av = make_float4(0.f, 0.f, 0.f, 0.f);
        int rr = rowBase + arow;
        if (rr < M) av = *(const float4*)(A + (size_t)rr * K + k0 + akc);
        As[akc + 0][arow] = av.x;
        As[akc + 1][arow] = av.y;
        As[akc + 2][arow] = av.z;
        As[akc + 3][arow] = av.w;
        float4 wv = *(const float4*)(W + (size_t)(k0 + wk) * D2 + colBase + wn0);
        Wshm[wk][wn0 + 0] = wv.x;
        Wshm[wk][wn0 + 1] = wv.y;
        Wshm[wk][wn0 + 2] = wv.z;
        Wshm[wk][wn0 + 3] = wv.w;
        __syncthreads();
#pragma unroll
        for (int kk = 0; kk < 16; ++kk) {
            float a0 = As[kk][(ty << 2) + 0], a1 = As[kk][(ty << 2) + 1];
            float a2 = As[kk][(ty << 2) + 2], a3 = As[kk][(ty << 2) + 3];
            float w0 = Wshm[kk][(tx << 2) + 0], w1 = Wshm[kk][(tx << 2) + 1];
            float w2 = Wshm[kk][(tx << 2) + 2], w3 = Wshm[kk][(tx << 2) + 3];
            acc[0][0] += a0 * w0; acc[0][1] += a0 * w1; acc[0][2] += a0 * w2; acc[0][3] += a0 * w3;
            acc[1][0] += a1 * w0; acc[1][1] += a1 * w1; acc[1][2] += a1 * w2; acc[1][3] += a1 * w3;
            acc[2][0] += a2 * w0; acc[2][1] += a2 * w1; acc[2][2] += a2 * w2; acc[2][3] += a2 * w3;
            acc[3][0] += a3 * w0; acc[3][1] += a3 * w1; acc[3][2] += a3 * w2; acc[3][3] += a3 * w3;
        }
        __syncthreads();
    }
#pragma unroll
    for (int i = 0; i < 4; ++i) {
        int rr = rowBase + (ty << 2) + i;
        if (rr >= M) continue;
        float* cp = C + (size_t)rr * D2 + colBase + (tx << 2);
        u16* cb = Cb + (size_t)rr * D2 + colBase + (tx << 2);
        cp[0] = acc[i][0]; cp[1] = acc[i][1]; cp[2] = acc[i][2]; cp[3] = acc[i][3];
        cb[0] = f2bf(acc[i][0]); cb[1] = f2bf(acc[i][1]);
        cb[2] = f2bf(acc[i][2]); cb[3] = f2bf(acc[i][3]);
    }
}

// ---- fused head: per-graph feats + final linear, one block per graph ----
__global__ __launch_bounds__(256) void k_fhead(
    const u16* __restrict__ x, const float* __restrict__ rel,
    const int* __restrict__ rel_labels,
    const float* __restrict__ lw, const float* __restrict__ lb,
    float* __restrict__ out) {
    int g = blockIdx.x, f = threadIdx.x;
    const u16* xg = x + (size_t)g * NPGN * D2;
    float s = 0.f;
#pragma unroll 8
    for (int n = 0; n < NPGN; ++n) s += bf2f(xg[(size_t)n * D2 + f]);
    float pooled = s * (1.0f / NPGN);
    float relv = rel[(size_t)rel_labels[g] * D2 + f];
    float hv = bf2f(xg[f]);
    float tv = bf2f(xg[D2 + f]);
    // partial dot over this thread's 4 k-positions: f, 256+f, 512+f, 768+f
    float a0 = pooled * lw[f * 2 + 0]        + relv * lw[(256 + f) * 2 + 0]
             + hv     * lw[(512 + f) * 2 + 0] + tv  * lw[(768 + f) * 2 + 0];
    float a1 = pooled * lw[f * 2 + 1]        + relv * lw[(256 + f) * 2 + 1]
             + hv     * lw[(512 + f) * 2 + 1] + tv  * lw[(768 + f) * 2 + 1];
    __shared__ float s0[256], s1[256];
    s0[f] = a0; s1[f] = a1;
    __syncthreads();
    for (int st = 128; st > 0; st >>= 1) {
        if (f < st) { s0[f] += s0[f + st]; s1[f] += s1[f + st]; }
        __syncthreads();
    }
    if (f == 0) {
        out[g * 2 + 0] = s0[0] + lb[0];
        out[g * 2 + 1] = s1[0] + lb[1];
    }
}

extern "C" void kernel_launch(void* const* d_in, const int* in_sizes, int n_in,
                              void* d_out, int out_size, void* d_ws, size_t ws_size,
                              hipStream_t stream) {
    const float* x0   = (const float*)d_in[0];
    const float* rel0 = (const float*)d_in[1];
    const int* edge_index = (const int*)d_in[20];
    const int* edge_type  = (const int*)d_in[21];
    const int* rel_labels = (const int*)d_in[23];
    float* out = (float*)d_out;

    // ---- workspace carve (~70 MB) ----
    float* ws = (float*)d_ws;
    float* relA  = ws;                              // RR*256
    float* relB  = relA + (size_t)RR * 256;         // RR*256
    float* dinv_in  = relB + (size_t)RR * 256;      // NN
    float* dinv_out = dinv_in + NN;                 // NN
    float* cnorm_in  = dinv_out + NN;               // EH
    float* cnorm_out = cnorm_in + EH;               // EH
    float* bnsums    = cnorm_out + EH;              // 512
    int* csrc_in  = (int*)(bnsums + 512);           // EH
    int* cet_in   = csrc_in + EH;                   // EH
    int* csrc_out = cet_in + EH;                    // EH
    int* cet_out  = csrc_out + EH;                  // EH
    int* off_in   = cet_out + EH;                   // NN+8
    int* off_out  = off_in + NN + 8;                // NN+8
    int* hs_in    = off_out + NN + 8;               // NN  -- zeroed region start
    int* hs_out   = hs_in + NN;                     // NN
    int* hd_in    = hs_out + NN;                    // NN
    int* hd_out   = hd_in + NN;                     // NN
    int* cur_in   = hd_out + NN;                    // NN
    int* cur_out  = cur_in + NN;                    // NN -- zeroed region end
    u16* xbf0 = (u16*)(cur_out + NN);               // NN*128 bf16
    u16* xbfA = xbf0 + (size_t)NN * 128;            // NN*256 bf16
    u16* aggI = xbfA + (size_t)NN * 256;            // NN*256 bf16
    u16* aggO = aggI + (size_t)NN * 256;            // NN*256 bf16
    u16* hb   = aggO + (size_t)NN * 256;            // NN*256 bf16 (pre-BN h)
    u16* wt0  = hb + (size_t)NN * 256;              // 3*256*128
    u16* wtS  = wt0 + 3 * 256 * 128;                // 12*256*256
    u16* relbf = wtS + 12 * 65536;                  // RR*256 bf16

    // ---- CSR build + conversions + weight prep (once per launch) ----
    hipMemsetAsync(hs_in, 0, 6 * NN * sizeof(int), stream);
    k_hist<<<ET / 256, 256, 0, stream>>>(edge_index, hs_in, hs_out, hd_in, hd_out);
    k_build<<<34, 1024, 0, stream>>>(hs_in, hs_out, dinv_in, dinv_out,
                                     hd_in, hd_out, off_in, off_out);
    k_fill2<<<dim3(EH / 256, 2), 256, 0, stream>>>(edge_index, edge_type,
        dinv_in, dinv_out, off_in, off_out, cur_in, cur_out,
        csrc_in, csrc_out, cet_in, cet_out, cnorm_in, cnorm_out);
    k_prep<<<2925, 256, 0, stream>>>(
        x0, xbf0, rel0, relbf,
        (const float*)d_in[2], (const float*)d_in[3], (const float*)d_in[4],
        (const float*)d_in[6], wt0, wt0 + 256 * D1, wt0 + 2 * 256 * D1,
        (const float*)d_in[10], (const float*)d_in[11], (const float*)d_in[12],
        (const float*)d_in[14], wtS, wtS + 4 * 65536, wtS + 8 * 65536);

    const float* rc = rel0; float* rn = relA;

    for (int l = 0; l < 5; ++l) {
        const int K = (l == 0) ? D1 : D2;
        const u16* xb = (l == 0) ? xbf0 : xbfA;
        const u16 *WiT, *WoT, *WlT;
        const float *Wr, *bias, *gamma, *beta;
        if (l == 0) {
            WiT = wt0; WoT = wt0 + 256 * D1; WlT = wt0 + 2 * 256 * D1;
            Wr = (const float*)d_in[5];
            bias  = (const float*)d_in[7];
            gamma = (const float*)d_in[8];
            beta  = (const float*)d_in[9];
        } else {
            int m = l - 1;
            WiT = wtS + (size_t)m * 65536;
            WoT = wtS + (size_t)(4 + m) * 65536;
            WlT = wtS + (size_t)(8 + m) * 65536;
            Wr = (const float*)d_in[13] + (size_t)m * D2 * D2;
            bias  = (const float*)d_in[15] + (size_t)m * D2;
            gamma = (const float*)d_in[16] + (size_t)m * D2;
            beta  = (const float*)d_in[17] + (size_t)m * D2;
        }

        // both-direction gather into bf16 agg buffers (zeroes bnsums too)
        if (K == D1) {
            dim3 ggr(NN / 16, 2);
            k_gather2<D1><<<ggr, 256, 0, stream>>>(xb, relbf, csrc_in, cet_in,
                cnorm_in, off_in, csrc_out, cet_out, cnorm_out, off_out, aggI, aggO, bnsums);
        } else {
            dim3 ggr(NN / 8, 2);
            k_gather2<D2><<<ggr, 256, 0, stream>>>(xb, relbf, csrc_in, cet_in,
                cnorm_in, off_in, csrc_out, cet_out, cnorm_out, off_out, aggI, aggO, bnsums);
        }
        // fused 3-segment MFMA GEMM (128x128 tiles) + BN stats, bf16 h out
        dim3 ggrid(NN / 128, 2);
        if (K == D1) k_gemm_mfma<D1><<<ggrid, 256, 0, stream>>>(aggI, aggO, xb, WiT, WoT, WlT, bias, hb, bnsums);
        else         k_gemm_mfma<D2><<<ggrid, 256, 0, stream>>>(aggI, aggO, xb, WiT, WoT, WlT, bias, hb, bnsums);
        // fused tail: BN apply + relu -> bf16 x, and rel chain GEMM (+bf16 copy)
        k_bnrel<<<4096 + 16, 256, 0, stream>>>((const u16x8*)hb, bnsums, gamma, beta,
                                               (u16x8*)xbfA, rc, Wr, rn, relbf, RR, K);
        const float* nr = rn;
        rn = (l == 0) ? relB : (float*)rc;
        rc = nr;
    }

    k_fhead<<<GG, 256, 0, stream>>>(xbfA, rc, rel_labels,
                                    (const float*)d_in[18], (const float*)d_in[19], out);
}